// Round 2
// baseline (7965.299 us; speedup 1.0000x reference)
//
#include <hip/hip_runtime.h>

#define L_ 6
#define H_ 8
#define C_ 512
#define V_ 32000
#define B_ 2
#define T_ 4096
#define Q_ 256
#define N_ 64
#define NC_ 16
#define M_ 8192   // B*T

typedef unsigned short u16;

__device__ __forceinline__ float bf2f(u16 u){
  return __uint_as_float(((unsigned int)u) << 16);
}
__device__ __forceinline__ u16 f2bf(float f){
  unsigned int x = __float_as_uint(f);
  return (u16)((x + 0x7fffu + ((x >> 16) & 1u)) >> 16);
}

// ---------------- dtype detection: bf16 weights never have |x|>=2 ----------------
// Probe first 2048 u16 of Wr. If data is fp32, ~half of the u16 halves are
// mantissa garbage with uniform exponents -> many with exp field >= 128.
__global__ __launch_bounds__(256) void detect_kernel(const void* __restrict__ probe,
                                                     int* __restrict__ flag){
  __shared__ int cnt;
  if (threadIdx.x == 0) cnt = 0;
  __syncthreads();
  const u16* p = (const u16*)probe;
  int c = 0;
  for (int i = threadIdx.x; i < 2048; i += 256){
    int e = (p[i] >> 7) & 0xFF;
    if (e >= 128) c++;
  }
  atomicAdd(&cnt, c);
  __syncthreads();
  if (threadIdx.x == 0) *flag = (cnt > 32) ? 1 : 0;  // 1 = inputs are fp32
}

// ---------------- canonicalize any input to bf16 ----------------
__global__ __launch_bounds__(256) void convert_kernel(const void* __restrict__ src,
    u16* __restrict__ dst, int n, const int* __restrict__ flag){
  const bool f32 = (*flag != 0);
  int stride = gridDim.x * 256;
  for (int i = blockIdx.x*256 + threadIdx.x; i < n; i += stride){
    dst[i] = f32 ? f2bf(((const float*)src)[i]) : ((const u16*)src)[i];
  }
}

// ---------------- embedding: x = wte[idx] + wpe ----------------
__global__ __launch_bounds__(256) void embed_kernel(const int* __restrict__ idx,
    const u16* __restrict__ wte, const u16* __restrict__ wpe, float* __restrict__ x){
  int row = blockIdx.x;                 // b*T + t
  int t = row & (T_-1);
  int tok = idx[row];
  const u16* we = wte + (size_t)tok * C_;
  const u16* wp = wpe + (size_t)t * C_;
  float* xo = x + (size_t)row * C_;
  int c = threadIdx.x;
  xo[c]     = bf2f(we[c])     + bf2f(wp[c]);
  xo[c+256] = bf2f(we[c+256]) + bf2f(wp[c+256]);
}

// ---------------- LayerNorm (no bias), row = one (b,t) ----------------
__global__ __launch_bounds__(256) void ln_kernel(const float* __restrict__ x,
    const u16* __restrict__ w, float* __restrict__ out, float eps){
  int row = blockIdx.x;
  const float* xr = x + (size_t)row*C_;
  float* orow = out + (size_t)row*C_;
  int c = threadIdx.x;
  float v0 = xr[c], v1 = xr[c+256];
  float s = v0+v1, ss = v0*v0+v1*v1;
  int lane = c & 63, wid = c >> 6;
  #pragma unroll
  for (int o=32;o>0;o>>=1){ s += __shfl_down(s,o,64); ss += __shfl_down(ss,o,64); }
  __shared__ float r1[4], r2[4];
  if (lane==0){ r1[wid]=s; r2[wid]=ss; }
  __syncthreads();
  if (c==0){
    float a=r1[0]+r1[1]+r1[2]+r1[3], bq=r2[0]+r2[1]+r2[2]+r2[3];
    float mu = a*(1.f/C_);
    float var = bq*(1.f/C_) - mu*mu;
    r1[0]=mu; r2[0]=rsqrtf(fmaxf(var,0.f)+eps);
  }
  __syncthreads();
  float mu=r1[0], inv=r2[0];
  orow[c]     = (v0-mu)*inv*bf2f(w[c]);
  orow[c+256] = (v1-mu)*inv*bf2f(w[c+256]);
}

// ---------------- final LN for last position only ----------------
__global__ __launch_bounds__(256) void lnf_last(const float* __restrict__ x,
    const u16* __restrict__ w, float* __restrict__ xf){
  int b = blockIdx.x;
  const float* xr = x + ((size_t)b*T_ + (T_-1))*C_;
  int c = threadIdx.x;
  float v0 = xr[c], v1 = xr[c+256];
  float s = v0+v1, ss = v0*v0+v1*v1;
  int lane = c & 63, wid = c >> 6;
  #pragma unroll
  for (int o=32;o>0;o>>=1){ s += __shfl_down(s,o,64); ss += __shfl_down(ss,o,64); }
  __shared__ float r1[4], r2[4];
  if (lane==0){ r1[wid]=s; r2[wid]=ss; }
  __syncthreads();
  if (c==0){
    float a=r1[0]+r1[1]+r1[2]+r1[3], bq=r2[0]+r2[1]+r2[2]+r2[3];
    float mu = a*(1.f/C_);
    float var = bq*(1.f/C_) - mu*mu;
    r1[0]=mu; r2[0]=rsqrtf(fmaxf(var,0.f)+1e-5f);
  }
  __syncthreads();
  float mu=r1[0], inv=r2[0];
  xf[b*C_+c]     = (v0-mu)*inv*bf2f(w[c]);
  xf[b*C_+c+256] = (v1-mu)*inv*bf2f(w[c+256]);
}

// ---------------- time-mix token shift: 4 outputs ----------------
__global__ __launch_bounds__(256) void tmix_mix_kernel(const float* __restrict__ xln,
    const u16* __restrict__ mk, const u16* __restrict__ mv,
    const u16* __restrict__ mr, const u16* __restrict__ mg,
    u16* __restrict__ xk, u16* __restrict__ xv, u16* __restrict__ xr, u16* __restrict__ xg){
  int row = blockIdx.x; int t = row & (T_-1);
  size_t off = (size_t)row*C_;
  const float* cur = xln + off;
  #pragma unroll
  for (int p=0;p<2;p++){
    int c = threadIdx.x + p*256;
    float xc = cur[c];
    float xp = t ? cur[c - C_] : 0.f;   // previous token (same batch), zero at t=0
    float xx = xp - xc;
    xk[off+c] = f2bf(xc + xx*bf2f(mk[c]));
    xv[off+c] = f2bf(xc + xx*bf2f(mv[c]));
    xr[off+c] = f2bf(xc + xx*bf2f(mr[c]));
    xg[off+c] = f2bf(xc + xx*bf2f(mg[c]));
  }
}

// ---------------- channel-mix token shift: 2 outputs ----------------
__global__ __launch_bounds__(256) void cmix_mix_kernel(const float* __restrict__ xln,
    const u16* __restrict__ mk, const u16* __restrict__ mr,
    u16* __restrict__ xk, u16* __restrict__ xr){
  int row = blockIdx.x; int t = row & (T_-1);
  size_t off = (size_t)row*C_;
  const float* cur = xln + off;
  #pragma unroll
  for (int p=0;p<2;p++){
    int c = threadIdx.x + p*256;
    float xc = cur[c];
    float xp = t ? cur[c - C_] : 0.f;
    float xx = xp - xc;
    xk[off+c] = f2bf(xc + xx*bf2f(mk[c]));
    xr[off+c] = f2bf(xc + xx*bf2f(mr[c]));
  }
}

// ---------------- GEMM: Y[M,N] = X[M,K] @ W[N,K]^T (bf16 in, fp32 acc) ----------------
#define BM_ 128
#define BN_ 128
#define BK_ 16

#define ACT_F32 0
#define ACT_RELU2_BF16 1
#define ACT_ADD_F32 2
#define ACT_BF16 3

template<int ACT>
__global__ __launch_bounds__(256) void gemm_bt(const u16* __restrict__ X, const u16* __restrict__ W,
    float* __restrict__ Yf, u16* __restrict__ Yb, int Mdim, int Ndim, int Kdim){
  __shared__ float As[BM_][BK_+1];
  __shared__ float Bs[BN_][BK_+1];
  const int bm = blockIdx.y * BM_;
  const int bn = blockIdx.x * BN_;
  const int tid = threadIdx.x;
  const int tx = tid & 15, ty = tid >> 4;
  float acc[8][8];
  #pragma unroll
  for (int i=0;i<8;i++)
    #pragma unroll
    for (int j=0;j<8;j++) acc[i][j]=0.f;
  const int lrow = tid >> 1;
  const int lk = (tid & 1) * 8;
  const u16* aptr = X + (size_t)(bm + lrow)*Kdim + lk;
  const u16* bptr = W + (size_t)(bn + lrow)*Kdim + lk;
  for (int k0=0; k0<Kdim; k0+=BK_){
    union { uint4 q; u16 h[8]; } ua, ub;
    ua.q = *(const uint4*)aptr;
    ub.q = *(const uint4*)bptr;
    aptr += BK_; bptr += BK_;
    #pragma unroll
    for (int j=0;j<8;j++){ As[lrow][lk+j]=bf2f(ua.h[j]); Bs[lrow][lk+j]=bf2f(ub.h[j]); }
    __syncthreads();
    for (int kk=0;kk<BK_;kk++){
      float a[8], b[8];
      #pragma unroll
      for (int i=0;i<8;i++) a[i]=As[ty*8+i][kk];
      #pragma unroll
      for (int j=0;j<8;j++) b[j]=Bs[tx*8+j][kk];
      #pragma unroll
      for (int i=0;i<8;i++)
        #pragma unroll
        for (int j=0;j<8;j++) acc[i][j] += a[i]*b[j];
    }
    __syncthreads();
  }
  #pragma unroll
  for (int i=0;i<8;i++){
    size_t m = (size_t)(bm + ty*8 + i);
    #pragma unroll
    for (int j=0;j<8;j++){
      size_t n = (size_t)(bn + tx*8 + j);
      size_t off = m*(size_t)Ndim + n;
      float v = acc[i][j];
      if (ACT==ACT_F32) Yf[off]=v;
      else if (ACT==ACT_RELU2_BF16){ float r = v>0.f?v:0.f; Yb[off]=f2bf(r*r); }
      else if (ACT==ACT_BF16) Yb[off]=f2bf(v);
      else Yf[off]+=v;
    }
  }
}

// ---------------- WKV intra-chunk: y = ((r@k^T) * Wmat) @ v ----------------
// grid: (NC_*4, B_*H_); block handles 64 rows (ip) of one chunk/head.
__global__ __launch_bounds__(256) void wkv_intra(const u16* __restrict__ Rb, const u16* __restrict__ Kb,
    const u16* __restrict__ Vb, const u16* __restrict__ td, const u16* __restrict__ tf,
    float* __restrict__ y){
  __shared__ float rs[64][68];
  __shared__ float kst[64][68];
  __shared__ float vst[64][68];
  __shared__ u16  At[64][72];
  __shared__ float wpow[Q_];
  const int c = blockIdx.x >> 2, ip = blockIdx.x & 3;
  const int bh = blockIdx.y, b = bh >> 3, h = bh & 7;
  const int tid = threadIdx.x, tx = tid & 15, ty = tid >> 4;
  const float wdec = expf(-expf(bf2f(td[h])));
  const float uu = bf2f(tf[h]);
  wpow[tid] = powf(wdec, (float)tid);
  const size_t base = ((size_t)b*T_ + (size_t)c*Q_)*C_ + h*N_;
  const int i0 = ip*64;
  {
    const int rr = tid >> 6, cc2 = tid & 63;
    for (int it=0; it<16; ++it){
      int i = it*4 + rr;
      rs[i][cc2] = bf2f(Rb[base + (size_t)(i0+i)*C_ + cc2]);
    }
  }
  float yacc[4][4] = {};
  for (int jt=0; jt<4; ++jt){
    __syncthreads();                       // protect kst/vst/At reuse (also covers wpow/rs staging)
    {
      const int rr = tid >> 6, cc2 = tid & 63;
      const int j0 = jt*64;
      for (int it=0; it<16; ++it){
        int j = it*4 + rr;
        kst[j][cc2] = bf2f(Kb[base + (size_t)(j0+j)*C_ + cc2]);
        vst[j][cc2] = bf2f(Vb[base + (size_t)(j0+j)*C_ + cc2]);
      }
    }
    __syncthreads();
    // matmul1: a1[ii][jj] = sum_n r[i0+4ty+ii][n] * k[jt*64 + jj*16+tx][n]
    float a1[4][4] = {};
    for (int n=0;n<N_;++n){
      float rv[4], kv[4];
      #pragma unroll
      for (int ii=0;ii<4;ii++) rv[ii]=rs[ty*4+ii][n];
      #pragma unroll
      for (int jj=0;jj<4;jj++) kv[jj]=kst[jj*16+tx][n];
      #pragma unroll
      for (int ii=0;ii<4;ii++)
        #pragma unroll
        for (int jj=0;jj<4;jj++) a1[ii][jj]+=rv[ii]*kv[jj];
    }
    // apply intra-chunk decay matrix, store A tile (bf16)
    #pragma unroll
    for (int ii=0;ii<4;ii++){
      int ic = i0 + ty*4+ii;               // chunk-local row
      #pragma unroll
      for (int jj=0;jj<4;jj++){
        int jc = jt*64 + jj*16+tx;         // chunk-local col
        float w = 0.f;
        if (jc < ic) w = wpow[ic-jc-1];
        else if (jc == ic) w = uu;
        At[ty*4+ii][jj*16+tx] = f2bf(a1[ii][jj]*w);
      }
    }
    __syncthreads();
    // matmul2: yacc += A_tile @ v_tile
    for (int jl=0;jl<64;++jl){
      float av[4], vv[4];
      #pragma unroll
      for (int ii=0;ii<4;ii++) av[ii]=bf2f(At[ty*4+ii][jl]);
      #pragma unroll
      for (int nn=0;nn<4;nn++) vv[nn]=vst[jl][tx*4+nn];
      #pragma unroll
      for (int ii=0;ii<4;ii++)
        #pragma unroll
        for (int nn=0;nn<4;nn++) yacc[ii][nn]+=av[ii]*vv[nn];
    }
  }
  #pragma unroll
  for (int ii=0;ii<4;ii++)
    #pragma unroll
    for (int nn=0;nn<4;nn++)
      y[base + (size_t)(i0+ty*4+ii)*C_ + tx*4+nn] = yacc[ii][nn];
}

// ---------------- per-chunk state contribution S_c = (k*wkv)^T @ v ----------------
__global__ __launch_bounds__(256) void wkv_state(const u16* __restrict__ Kb, const u16* __restrict__ Vb,
    const u16* __restrict__ td, float* __restrict__ S){
  __shared__ float kst[64][68];
  __shared__ float vst[64][68];
  __shared__ float wpow[Q_];
  const int c = blockIdx.x, bh = blockIdx.y, b = bh>>3, h = bh&7;
  const int tid = threadIdx.x, tx = tid&15, ty = tid>>4;
  const float wdec = expf(-expf(bf2f(td[h])));
  wpow[tid] = powf(wdec, (float)tid);
  const size_t base = ((size_t)b*T_ + (size_t)c*Q_)*C_ + h*N_;
  float acc[4][4] = {};
  for (int jt=0;jt<4;++jt){
    __syncthreads();
    {
      const int rr = tid >> 6, cc2 = tid & 63;
      const int j0 = jt*64;
      for (int it=0; it<16; ++it){
        int j = it*4 + rr;
        kst[j][cc2] = bf2f(Kb[base + (size_t)(j0+j)*C_ + cc2]);
        vst[j][cc2] = bf2f(Vb[base + (size_t)(j0+j)*C_ + cc2]);
      }
    }
    __syncthreads();
    for (int jl=0;jl<64;++jl){
      float f = wpow[Q_-1-(jt*64+jl)];
      float kv[4], vv[4];
      #pragma unroll
      for (int mm=0;mm<4;mm++) kv[mm]=kst[jl][ty*4+mm]*f;
      #pragma unroll
      for (int nn=0;nn<4;nn++) vv[nn]=vst[jl][tx*4+nn];
      #pragma unroll
      for (int mm=0;mm<4;mm++)
        #pragma unroll
        for (int nn=0;nn<4;nn++) acc[mm][nn]+=kv[mm]*vv[nn];
    }
  }
  float* Sp = S + ((size_t)bh*NC_ + c)*(N_*N_);
  #pragma unroll
  for (int mm=0;mm<4;mm++)
    #pragma unroll
    for (int nn=0;nn<4;nn++)
      Sp[(ty*4+mm)*N_ + tx*4+nn] = acc[mm][nn];
}

// ---------------- sequential prefix over chunks (in-place: S[c] := incoming state) ----------------
__global__ __launch_bounds__(256) void wkv_prefix(float* __restrict__ S, const u16* __restrict__ td){
  const int bh = blockIdx.x, h = bh&7;
  const float wdec = expf(-expf(bf2f(td[h])));
  const float wsd = powf(wdec, (float)Q_);
  float* Sp = S + (size_t)bh*NC_*N_*N_;
  for (int e=threadIdx.x; e<N_*N_; e+=256){
    float cur = 0.f;
    for (int cc=0;cc<NC_;++cc){
      float sc = Sp[(size_t)cc*N_*N_ + e];
      Sp[(size_t)cc*N_*N_ + e] = cur;
      cur = wsd*cur + sc;
    }
  }
}

// ---------------- inter-chunk: y += (r @ state_c) * wdec^i ----------------
__global__ __launch_bounds__(256) void wkv_inter(const u16* __restrict__ Rb, const float* __restrict__ S,
    const u16* __restrict__ td, float* __restrict__ y){
  __shared__ float st[64][65];
  __shared__ float rs[64][68];
  __shared__ float wpow[Q_];
  const int c = blockIdx.x>>2, ip = blockIdx.x&3;
  const int bh = blockIdx.y, b = bh>>3, h = bh&7;
  const int tid = threadIdx.x, tx = tid&15, ty = tid>>4;
  const float wdec = expf(-expf(bf2f(td[h])));
  wpow[tid] = powf(wdec, (float)tid);
  const float* Sp = S + ((size_t)bh*NC_ + c)*(N_*N_);
  for (int e=tid;e<N_*N_;e+=256) st[e>>6][e&63] = Sp[e];
  const size_t base = ((size_t)b*T_ + (size_t)c*Q_)*C_ + h*N_;
  const int i0 = ip*64;
  {
    const int rr = tid >> 6, cc2 = tid & 63;
    for (int it=0;it<16;++it){ int i=it*4+rr; rs[i][cc2]=bf2f(Rb[base+(size_t)(i0+i)*C_+cc2]); }
  }
  __syncthreads();
  float acc[4][4] = {};
  for (int kk=0;kk<N_;++kk){
    float rv[4], sv[4];
    #pragma unroll
    for (int ii=0;ii<4;ii++) rv[ii]=rs[ty*4+ii][kk];
    #pragma unroll
    for (int nn=0;nn<4;nn++) sv[nn]=st[kk][tx*4+nn];
    #pragma unroll
    for (int ii=0;ii<4;ii++)
      #pragma unroll
      for (int nn=0;nn<4;nn++) acc[ii][nn]+=rv[ii]*sv[nn];
  }
  #pragma unroll
  for (int ii=0;ii<4;ii++){
    int il = i0+ty*4+ii;
    #pragma unroll
    for (int nn=0;nn<4;nn++)
      y[base + (size_t)il*C_ + tx*4+nn] += wpow[il]*acc[ii][nn];
  }
}

// ---------------- GroupNorm over head dim + *silu(g), bf16 out ----------------
__global__ __launch_bounds__(64) void gn_kernel(const float* __restrict__ y, const u16* __restrict__ gnw,
    const u16* __restrict__ gnb, const u16* __restrict__ g, u16* __restrict__ out){
  const int id = blockIdx.x;           // (b*T_+t)*H_ + h
  const int h = id & 7;
  const size_t rowc = (size_t)(id >> 3);
  const int lane = threadIdx.x;
  const size_t off = rowc*C_ + h*N_ + lane;
  float v = y[off];
  float s = v, ss = v*v;
  #pragma unroll
  for (int o=32;o>0;o>>=1){ s+=__shfl_xor(s,o,64); ss+=__shfl_xor(ss,o,64); }
  float mu = s*(1.f/N_);
  float var = ss*(1.f/N_) - mu*mu;
  float inv = rsqrtf(fmaxf(var,0.f) + 6.4e-4f);   // GN_EPS = 1e-5*64
  int ci = h*N_+lane;
  float gg = bf2f(g[off]);
  float sil = gg/(1.f+expf(-gg));
  out[off] = f2bf(((v-mu)*inv*bf2f(gnw[ci]) + bf2f(gnb[ci]))*sil);
}

// ---------------- channel-mix tail: x += sigmoid(rr) * hv ----------------
__global__ __launch_bounds__(256) void cmix_fuse(const float* __restrict__ rr,
    const float* __restrict__ hv, float* __restrict__ x){
  size_t i = (size_t)blockIdx.x*256 + threadIdx.x;
  float r = rr[i];
  x[i] += hv[i]/(1.f+expf(-r));
}

// ---------------- logits for last position: [B,V] = xf @ wte^T ----------------
__global__ __launch_bounds__(256) void logits_kernel(const float* __restrict__ xf,
    const u16* __restrict__ wte, void* __restrict__ out, const int* __restrict__ flag){
  const int wid = threadIdx.x>>6, lane = threadIdx.x&63;
  const int gw = blockIdx.x*4 + wid;     // 0 .. B*V-1
  const int b = gw / V_, v = gw - b*V_;
  const u16* wrow = wte + (size_t)v*C_;
  const float* xr = xf + b*C_;
  union {uint4 q; u16 h[8];} uu;
  uu.q = *(const uint4*)(wrow + lane*8);
  float s = 0.f;
  #pragma unroll
  for (int j=0;j<8;j++) s += bf2f(uu.h[j])*xr[lane*8+j];
  #pragma unroll
  for (int o=32;o>0;o>>=1) s += __shfl_down(s,o,64);
  if (lane==0){
    size_t o = (size_t)b*V_ + v;
    if (*flag) ((float*)out)[o] = s;          // fp32 harness
    else       ((u16*)out)[o]   = f2bf(s);    // bf16 harness
  }
}

extern "C" void kernel_launch(void* const* d_in, const int* in_sizes, int n_in,
                              void* d_out, int out_size, void* d_ws, size_t ws_size,
                              hipStream_t stream){
  (void)out_size; (void)ws_size;
  const int* idx  = (const int*)d_in[0];

  char* ws = (char*)d_ws;
  const size_t MC  = (size_t)M_*C_;
  // ---- workspace layout (bytes) ----
  size_t o = 0;
  int* flag = (int*)(ws + o);            o += 1024;
  float* X   = (float*)(ws + o);         o += MC*4;            // fp32 residual
  float* XLN = (float*)(ws + o);         o += MC*4;            // also Y / HV
  float* Y  = XLN;  float* HV = XLN;
  u16* MK = (u16*)(ws + o);              o += MC*2;            // also YGN
  u16* MV = (u16*)(ws + o);              o += MC*2;
  u16* MR = (u16*)(ws + o);              o += MC*2;            // also S (4MB)
  u16* MG = (u16*)(ws + o);              o += MC*2;
  u16* Rb = (u16*)(ws + o);              o += MC*2;            // H1 spans Rb..Vb
  u16* Kb = (u16*)(ws + o);              o += MC*2;
  u16* Vb = (u16*)(ws + o);              o += MC*2;            // RR spans Vb..Gb
  u16* Gb = (u16*)(ws + o);              o += MC*2;
  float* XF = (float*)(ws + o);          o += 65536;
  u16* pool = (u16*)(ws + o);            // canonical bf16 inputs
  u16* YGN = MK;
  float* S  = (float*)MR;
  u16* H1 = Rb;
  float* RR = (float*)Vb;

  // ---- dtype detect + canonicalize all non-integer inputs ----
  detect_kernel<<<1,256,0,stream>>>(d_in[12], flag);   // probe Wr
  u16* cw[24];
  {
    size_t poff = 0;
    for (int i=1;i<24;i++){ cw[i] = pool + poff; poff += (size_t)in_sizes[i]; }
  }
  for (int i=1;i<24;i++){
    int n = in_sizes[i];
    int blocks = (n + 255)/256; if (blocks > 4096) blocks = 4096;
    convert_kernel<<<blocks,256,0,stream>>>(d_in[i], cw[i], n, flag);
  }
  const u16* wte  = cw[1];  const u16* wpe  = cw[2];
  const u16* ln1w = cw[3];  const u16* ln2w = cw[4];  const u16* lnfw = cw[5];
  const u16* maak = cw[6];  const u16* maav = cw[7];
  const u16* maar = cw[8];  const u16* maag = cw[9];
  const u16* tdec = cw[10]; const u16* tfir = cw[11];
  const u16* Wr   = cw[12]; const u16* Wk   = cw[13]; const u16* Wv   = cw[14];
  const u16* Wg   = cw[15]; const u16* Wo   = cw[16];
  const u16* gnw  = cw[17]; const u16* gnb  = cw[18];
  const u16* cmk  = cw[19]; const u16* cmr  = cw[20];
  const u16* Wck  = cw[21]; const u16* Wcv  = cw[22]; const u16* Wcr  = cw[23];

  embed_kernel<<<M_,256,0,stream>>>(idx,wte,wpe,X);
  dim3 gsq(C_/BN_, M_/BM_);      // (4,64)
  dim3 gck(3*C_/BN_, M_/BM_);    // (12,64)
  for (int l=0;l<L_;++l){
    // ---- time mix ----
    ln_kernel<<<M_,256,0,stream>>>(X, ln1w+l*C_, XLN, 1e-5f);
    tmix_mix_kernel<<<M_,256,0,stream>>>(XLN, maak+l*C_, maav+l*C_, maar+l*C_, maag+l*C_,
                                         MK,MV,MR,MG);
    gemm_bt<ACT_BF16><<<gsq,256,0,stream>>>(MR, Wr+(size_t)l*C_*C_, nullptr, Rb, M_, C_, C_);
    gemm_bt<ACT_BF16><<<gsq,256,0,stream>>>(MK, Wk+(size_t)l*C_*C_, nullptr, Kb, M_, C_, C_);
    gemm_bt<ACT_BF16><<<gsq,256,0,stream>>>(MV, Wv+(size_t)l*C_*C_, nullptr, Vb, M_, C_, C_);
    gemm_bt<ACT_BF16><<<gsq,256,0,stream>>>(MG, Wg+(size_t)l*C_*C_, nullptr, Gb, M_, C_, C_);
    wkv_intra<<<dim3(NC_*4, B_*H_),256,0,stream>>>(Rb,Kb,Vb, tdec+l*H_, tfir+l*H_, Y);
    wkv_state<<<dim3(NC_,   B_*H_),256,0,stream>>>(Kb,Vb, tdec+l*H_, S);
    wkv_prefix<<<B_*H_,256,0,stream>>>(S, tdec+l*H_);
    wkv_inter<<<dim3(NC_*4, B_*H_),256,0,stream>>>(Rb, S, tdec+l*H_, Y);
    gn_kernel<<<M_*H_,64,0,stream>>>(Y, gnw+l*C_, gnb+l*C_, Gb, YGN);
    gemm_bt<ACT_ADD_F32><<<gsq,256,0,stream>>>(YGN, Wo+(size_t)l*C_*C_, X, nullptr, M_, C_, C_);
    // ---- channel mix ----
    ln_kernel<<<M_,256,0,stream>>>(X, ln2w+l*C_, XLN, 1e-5f);
    cmix_mix_kernel<<<M_,256,0,stream>>>(XLN, cmk+l*C_, cmr+l*C_, MK, MV);
    gemm_bt<ACT_RELU2_BF16><<<gck,256,0,stream>>>(MK, Wck+(size_t)l*3*C_*C_, nullptr, H1, M_, 3*C_, C_);
    gemm_bt<ACT_F32><<<gsq,256,0,stream>>>(H1, Wcv+(size_t)l*C_*3*C_, HV, nullptr, M_, C_, 3*C_);
    gemm_bt<ACT_F32><<<gsq,256,0,stream>>>(MV, Wcr+(size_t)l*C_*C_, RR, nullptr, M_, C_, C_);
    cmix_fuse<<<(M_*C_)/256,256,0,stream>>>(RR, HV, X);
  }
  lnf_last<<<B_,256,0,stream>>>(X, lnfw, XF);
  logits_kernel<<<(B_*V_)/4,256,0,stream>>>(XF, wte, d_out, flag);
}

// Round 4
// 2182.979 us; speedup vs baseline: 3.6488x; 3.6488x over previous
//
#include <hip/hip_runtime.h>

#define L_ 6
#define H_ 8
#define C_ 512
#define V_ 32000
#define B_ 2
#define T_ 4096
#define Q_ 256
#define N_ 64
#define NC_ 16
#define M_ 8192   // B*T

typedef unsigned short u16;
typedef __attribute__((ext_vector_type(8))) short bf16x8;
typedef __attribute__((ext_vector_type(4))) float f32x4;

__device__ __forceinline__ float bf2f(u16 u){
  return __uint_as_float(((unsigned int)u) << 16);
}
__device__ __forceinline__ u16 f2bf(float f){
  unsigned int x = __float_as_uint(f);
  return (u16)((x + 0x7fffu + ((x >> 16) & 1u)) >> 16);
}

__device__ __forceinline__ void gl_lds16(const u16* g, u16* l){
  __builtin_amdgcn_global_load_lds((const __attribute__((address_space(1))) void*)g,
                                   (__attribute__((address_space(3))) void*)l, 16, 0, 0);
}

// ---------------- dtype detection: bf16 weights never have |x|>=2 ----------------
__global__ __launch_bounds__(256) void detect_kernel(const void* __restrict__ probe,
                                                     int* __restrict__ flag){
  __shared__ int cnt;
  if (threadIdx.x == 0) cnt = 0;
  __syncthreads();
  const u16* p = (const u16*)probe;
  int c = 0;
  for (int i = threadIdx.x; i < 2048; i += 256){
    int e = (p[i] >> 7) & 0xFF;
    if (e >= 128) c++;
  }
  atomicAdd(&cnt, c);
  __syncthreads();
  if (threadIdx.x == 0) *flag = (cnt > 32) ? 1 : 0;  // 1 = inputs are fp32
}

// ---------------- canonicalize any input to bf16 ----------------
__global__ __launch_bounds__(256) void convert_kernel(const void* __restrict__ src,
    u16* __restrict__ dst, int n, const int* __restrict__ flag){
  const bool f32 = (*flag != 0);
  int stride = gridDim.x * 256;
  for (int i = blockIdx.x*256 + threadIdx.x; i < n; i += stride){
    dst[i] = f32 ? f2bf(((const float*)src)[i]) : ((const u16*)src)[i];
  }
}

// ---------------- embedding: x = wte[idx] + wpe ----------------
__global__ __launch_bounds__(256) void embed_kernel(const int* __restrict__ idx,
    const u16* __restrict__ wte, const u16* __restrict__ wpe, float* __restrict__ x){
  int row = blockIdx.x;                 // b*T + t
  int t = row & (T_-1);
  int tok = idx[row];
  const u16* we = wte + (size_t)tok * C_;
  const u16* wp = wpe + (size_t)t * C_;
  float* xo = x + (size_t)row * C_;
  int c = threadIdx.x;
  xo[c]     = bf2f(we[c])     + bf2f(wp[c]);
  xo[c+256] = bf2f(we[c+256]) + bf2f(wp[c+256]);
}

// ---------------- LayerNorm (no bias), row = one (b,t) ----------------
__global__ __launch_bounds__(256) void ln_kernel(const float* __restrict__ x,
    const u16* __restrict__ w, float* __restrict__ out, float eps){
  int row = blockIdx.x;
  const float* xr = x + (size_t)row*C_;
  float* orow = out + (size_t)row*C_;
  int c = threadIdx.x;
  float v0 = xr[c], v1 = xr[c+256];
  float s = v0+v1, ss = v0*v0+v1*v1;
  int lane = c & 63, wid = c >> 6;
  #pragma unroll
  for (int o=32;o>0;o>>=1){ s += __shfl_down(s,o,64); ss += __shfl_down(ss,o,64); }
  __shared__ float r1[4], r2[4];
  if (lane==0){ r1[wid]=s; r2[wid]=ss; }
  __syncthreads();
  if (c==0){
    float a=r1[0]+r1[1]+r1[2]+r1[3], bq=r2[0]+r2[1]+r2[2]+r2[3];
    float mu = a*(1.f/C_);
    float var = bq*(1.f/C_) - mu*mu;
    r1[0]=mu; r2[0]=rsqrtf(fmaxf(var,0.f)+eps);
  }
  __syncthreads();
  float mu=r1[0], inv=r2[0];
  orow[c]     = (v0-mu)*inv*bf2f(w[c]);
  orow[c+256] = (v1-mu)*inv*bf2f(w[c+256]);
}

// ---------------- final LN for last position only ----------------
__global__ __launch_bounds__(256) void lnf_last(const float* __restrict__ x,
    const u16* __restrict__ w, float* __restrict__ xf){
  int b = blockIdx.x;
  const float* xr = x + ((size_t)b*T_ + (T_-1))*C_;
  int c = threadIdx.x;
  float v0 = xr[c], v1 = xr[c+256];
  float s = v0+v1, ss = v0*v0+v1*v1;
  int lane = c & 63, wid = c >> 6;
  #pragma unroll
  for (int o=32;o>0;o>>=1){ s += __shfl_down(s,o,64); ss += __shfl_down(ss,o,64); }
  __shared__ float r1[4], r2[4];
  if (lane==0){ r1[wid]=s; r2[wid]=ss; }
  __syncthreads();
  if (c==0){
    float a=r1[0]+r1[1]+r1[2]+r1[3], bq=r2[0]+r2[1]+r2[2]+r2[3];
    float mu = a*(1.f/C_);
    float var = bq*(1.f/C_) - mu*mu;
    r1[0]=mu; r2[0]=rsqrtf(fmaxf(var,0.f)+1e-5f);
  }
  __syncthreads();
  float mu=r1[0], inv=r2[0];
  xf[b*C_+c]     = (v0-mu)*inv*bf2f(w[c]);
  xf[b*C_+c+256] = (v1-mu)*inv*bf2f(w[c+256]);
}

// ---------------- time-mix token shift: 4 outputs ----------------
__global__ __launch_bounds__(256) void tmix_mix_kernel(const float* __restrict__ xln,
    const u16* __restrict__ mk, const u16* __restrict__ mv,
    const u16* __restrict__ mr, const u16* __restrict__ mg,
    u16* __restrict__ xk, u16* __restrict__ xv, u16* __restrict__ xr, u16* __restrict__ xg){
  int row = blockIdx.x; int t = row & (T_-1);
  size_t off = (size_t)row*C_;
  const float* cur = xln + off;
  #pragma unroll
  for (int p=0;p<2;p++){
    int c = threadIdx.x + p*256;
    float xc = cur[c];
    float xp = t ? cur[c - C_] : 0.f;   // previous token (same batch), zero at t=0
    float xx = xp - xc;
    xk[off+c] = f2bf(xc + xx*bf2f(mk[c]));
    xv[off+c] = f2bf(xc + xx*bf2f(mv[c]));
    xr[off+c] = f2bf(xc + xx*bf2f(mr[c]));
    xg[off+c] = f2bf(xc + xx*bf2f(mg[c]));
  }
}

// ---------------- channel-mix token shift: 2 outputs ----------------
__global__ __launch_bounds__(256) void cmix_mix_kernel(const float* __restrict__ xln,
    const u16* __restrict__ mk, const u16* __restrict__ mr,
    u16* __restrict__ xk, u16* __restrict__ xr){
  int row = blockIdx.x; int t = row & (T_-1);
  size_t off = (size_t)row*C_;
  const float* cur = xln + off;
  #pragma unroll
  for (int p=0;p<2;p++){
    int c = threadIdx.x + p*256;
    float xc = cur[c];
    float xp = t ? cur[c - C_] : 0.f;
    float xx = xp - xc;
    xk[off+c] = f2bf(xc + xx*bf2f(mk[c]));
    xr[off+c] = f2bf(xc + xx*bf2f(mr[c]));
  }
}

// ================= MFMA GEMM: Y[M,N] = X[M,K] @ W[N,K]^T =================
// m97 structure: 128x128 tile, BK=64, global_load_lds(16B), 16x16x32 bf16 MFMA,
// 4 waves, each computes 64x64 (4x4 fragments). 2-barrier K-loop.
#define ACT_F32 0
#define ACT_RELU2_BF16 1
#define ACT_ADD_F32 2
#define ACT_BF16 3

template<int ACT>
__device__ __forceinline__ void gemm_mfma_body(const u16* __restrict__ X, const u16* __restrict__ W,
    float* __restrict__ Yf, u16* __restrict__ Yb, int Ndim, int Kdim, int bm, int bn){
  __shared__ __align__(16) u16 Al[128*64];
  __shared__ __align__(16) u16 Bl[128*64];
  const int tid = threadIdx.x;
  const int wv = tid >> 6, ln = tid & 63;
  const int m16 = ln & 15, q = ln >> 4;
  const int wm = (wv & 1)*64, wn = (wv >> 1)*64;

  f32x4 acc[4][4];
  #pragma unroll
  for (int i=0;i<4;i++)
    #pragma unroll
    for (int j=0;j<4;j++) acc[i][j] = f32x4{0.f,0.f,0.f,0.f};

  // staging map: instruction s, wave wv, lane ln -> tile row/col
  // lds elem offset = s*2048 + wv*512 + ln*8 ; row = s*32 + wv*8 + ln/8 ; col = (ln%8)*8
  const int r0 = wv*8 + (ln >> 3);
  const int c0 = (ln & 7)*8;
  const u16* ga = X + (size_t)(bm + r0)*Kdim + c0;
  const u16* gb = W + (size_t)(bn + r0)*Kdim + c0;
  u16* la = Al + r0*64 + c0;
  u16* lb = Bl + r0*64 + c0;

  for (int k0=0; k0<Kdim; k0+=64){
    #pragma unroll
    for (int s=0;s<4;s++){
      gl_lds16(ga + (size_t)(s*32)*Kdim + k0, la + s*2048);
      gl_lds16(gb + (size_t)(s*32)*Kdim + k0, lb + s*2048);
    }
    __syncthreads();   // compiler emits vmcnt(0) drain before barrier
    #pragma unroll
    for (int kh=0; kh<2; kh++){
      bf16x8 af[4], bfr[4];
      #pragma unroll
      for (int i=0;i<4;i++) af[i]  = *(const bf16x8*)(Al + (wm + i*16 + m16)*64 + kh*32 + q*8);
      #pragma unroll
      for (int j=0;j<4;j++) bfr[j] = *(const bf16x8*)(Bl + (wn + j*16 + m16)*64 + kh*32 + q*8);
      #pragma unroll
      for (int i=0;i<4;i++)
        #pragma unroll
        for (int j=0;j<4;j++)
          acc[i][j] = __builtin_amdgcn_mfma_f32_16x16x32_bf16(af[i], bfr[j], acc[i][j], 0, 0, 0);
    }
    __syncthreads();
  }

  // epilogue: C/D layout col=lane&15, row=quad*4+reg
  #pragma unroll
  for (int i=0;i<4;i++){
    int row = bm + wm + i*16 + q*4;
    #pragma unroll
    for (int j=0;j<4;j++){
      int col = bn + wn + j*16 + m16;
      #pragma unroll
      for (int r=0;r<4;r++){
        size_t off = (size_t)(row + r)*Ndim + col;
        float v = acc[i][j][r];
        if (ACT==ACT_F32) Yf[off] = v;
        else if (ACT==ACT_RELU2_BF16){ float rr = v>0.f ? v : 0.f; Yb[off] = f2bf(rr*rr); }
        else if (ACT==ACT_BF16) Yb[off] = f2bf(v);
        else Yf[off] += v;
      }
    }
  }
}

template<int ACT>
__global__ __launch_bounds__(256,2) void gemm_mfma(const u16* __restrict__ X, const u16* __restrict__ W,
    float* __restrict__ Yf, u16* __restrict__ Yb, int Ndim, int Kdim){
  gemm_mfma_body<ACT>(X, W, Yf, Yb, Ndim, Kdim, blockIdx.y*128, blockIdx.x*128);
}

// fused r/k/v/g projections: z selects (input mix buffer, weight, output)
__global__ __launch_bounds__(256,2) void gemm4_mfma(const u16* __restrict__ Abase,
    const u16* __restrict__ W0, const u16* __restrict__ W1,
    const u16* __restrict__ W2, const u16* __restrict__ W3,
    u16* __restrict__ Obase){
  const size_t MC = (size_t)M_*C_;
  const int z = blockIdx.z;
  const u16* X; const u16* W;
  switch (z){
    case 0:  X = Abase + 2*MC; W = W0; break;   // Rb <- MR @ Wr
    case 1:  X = Abase;        W = W1; break;   // Kb <- MK @ Wk
    case 2:  X = Abase + 1*MC; W = W2; break;   // Vb <- MV @ Wv
    default: X = Abase + 3*MC; W = W3; break;   // Gb <- MG @ Wg
  }
  gemm_mfma_body<ACT_BF16>(X, W, nullptr, Obase + (size_t)z*MC, C_, C_,
                           blockIdx.y*128, blockIdx.x*128);
}

// fused cmix value+receptance GEMMs: z=0 -> HV = H1 @ Wcv^T (K=3C), z=1 -> RR = MV @ Wcr^T (K=C)
// NOTE: RR must NOT alias H1 (z=0 reads H1 concurrently with z=1's RR writes).
__global__ __launch_bounds__(256,2) void gemm2_mfma(const u16* __restrict__ H1, const u16* __restrict__ Wcv,
    const u16* __restrict__ MV, const u16* __restrict__ Wcr,
    float* __restrict__ HV, float* __restrict__ RR){
  if (blockIdx.z == 0)
    gemm_mfma_body<ACT_F32>(H1, Wcv, HV, nullptr, C_, 3*C_, blockIdx.y*128, blockIdx.x*128);
  else
    gemm_mfma_body<ACT_F32>(MV, Wcr, RR, nullptr, C_, C_, blockIdx.y*128, blockIdx.x*128);
}

// ---------------- WKV intra-chunk: y = ((r@k^T) * Wmat) @ v ----------------
__global__ __launch_bounds__(256) void wkv_intra(const u16* __restrict__ Rb, const u16* __restrict__ Kb,
    const u16* __restrict__ Vb, const u16* __restrict__ td, const u16* __restrict__ tf,
    float* __restrict__ y){
  __shared__ float rs[64][68];
  __shared__ float kst[64][68];
  __shared__ float vst[64][68];
  __shared__ u16  At[64][72];
  __shared__ float wpow[Q_];
  const int c = blockIdx.x >> 2, ip = blockIdx.x & 3;
  const int bh = blockIdx.y, b = bh >> 3, h = bh & 7;
  const int tid = threadIdx.x, tx = tid & 15, ty = tid >> 4;
  const float wdec = expf(-expf(bf2f(td[h])));
  const float uu = bf2f(tf[h]);
  wpow[tid] = powf(wdec, (float)tid);
  const size_t base = ((size_t)b*T_ + (size_t)c*Q_)*C_ + h*N_;
  const int i0 = ip*64;
  {
    const int rr = tid >> 6, cc2 = tid & 63;
    for (int it=0; it<16; ++it){
      int i = it*4 + rr;
      rs[i][cc2] = bf2f(Rb[base + (size_t)(i0+i)*C_ + cc2]);
    }
  }
  float yacc[4][4] = {};
  for (int jt=0; jt<4; ++jt){
    __syncthreads();
    {
      const int rr = tid >> 6, cc2 = tid & 63;
      const int j0 = jt*64;
      for (int it=0; it<16; ++it){
        int j = it*4 + rr;
        kst[j][cc2] = bf2f(Kb[base + (size_t)(j0+j)*C_ + cc2]);
        vst[j][cc2] = bf2f(Vb[base + (size_t)(j0+j)*C_ + cc2]);
      }
    }
    __syncthreads();
    float a1[4][4] = {};
    for (int n=0;n<N_;++n){
      float rv[4], kv[4];
      #pragma unroll
      for (int ii=0;ii<4;ii++) rv[ii]=rs[ty*4+ii][n];
      #pragma unroll
      for (int jj=0;jj<4;jj++) kv[jj]=kst[jj*16+tx][n];
      #pragma unroll
      for (int ii=0;ii<4;ii++)
        #pragma unroll
        for (int jj=0;jj<4;jj++) a1[ii][jj]+=rv[ii]*kv[jj];
    }
    #pragma unroll
    for (int ii=0;ii<4;ii++){
      int ic = i0 + ty*4+ii;
      #pragma unroll
      for (int jj=0;jj<4;jj++){
        int jc = jt*64 + jj*16+tx;
        float w = 0.f;
        if (jc < ic) w = wpow[ic-jc-1];
        else if (jc == ic) w = uu;
        At[ty*4+ii][jj*16+tx] = f2bf(a1[ii][jj]*w);
      }
    }
    __syncthreads();
    for (int jl=0;jl<64;++jl){
      float av[4], vv[4];
      #pragma unroll
      for (int ii=0;ii<4;ii++) av[ii]=bf2f(At[ty*4+ii][jl]);
      #pragma unroll
      for (int nn=0;nn<4;nn++) vv[nn]=vst[jl][tx*4+nn];
      #pragma unroll
      for (int ii=0;ii<4;ii++)
        #pragma unroll
        for (int nn=0;nn<4;nn++) yacc[ii][nn]+=av[ii]*vv[nn];
    }
  }
  #pragma unroll
  for (int ii=0;ii<4;ii++)
    #pragma unroll
    for (int nn=0;nn<4;nn++)
      y[base + (size_t)(i0+ty*4+ii)*C_ + tx*4+nn] = yacc[ii][nn];
}

// ---------------- per-chunk state contribution S_c = (k*wkv)^T @ v ----------------
__global__ __launch_bounds__(256) void wkv_state(const u16* __restrict__ Kb, const u16* __restrict__ Vb,
    const u16* __restrict__ td, float* __restrict__ S){
  __shared__ float kst[64][68];
  __shared__ float vst[64][68];
  __shared__ float wpow[Q_];
  const int c = blockIdx.x, bh = blockIdx.y, b = bh>>3, h = bh&7;
  const int tid = threadIdx.x, tx = tid&15, ty = tid>>4;
  const float wdec = expf(-expf(bf2f(td[h])));
  wpow[tid] = powf(wdec, (float)tid);
  const size_t base = ((size_t)b*T_ + (size_t)c*Q_)*C_ + h*N_;
  float acc[4][4] = {};
  for (int jt=0;jt<4;++jt){
    __syncthreads();
    {
      const int rr = tid >> 6, cc2 = tid & 63;
      const int j0 = jt*64;
      for (int it=0; it<16; ++it){
        int j = it*4 + rr;
        kst[j][cc2] = bf2f(Kb[base + (size_t)(j0+j)*C_ + cc2]);
        vst[j][cc2] = bf2f(Vb[base + (size_t)(j0+j)*C_ + cc2]);
      }
    }
    __syncthreads();
    for (int jl=0;jl<64;++jl){
      float f = wpow[Q_-1-(jt*64+jl)];
      float kv[4], vv[4];
      #pragma unroll
      for (int mm=0;mm<4;mm++) kv[mm]=kst[jl][ty*4+mm]*f;
      #pragma unroll
      for (int nn=0;nn<4;nn++) vv[nn]=vst[jl][tx*4+nn];
      #pragma unroll
      for (int mm=0;mm<4;mm++)
        #pragma unroll
        for (int nn=0;nn<4;nn++) acc[mm][nn]+=kv[mm]*vv[nn];
    }
  }
  float* Sp = S + ((size_t)bh*NC_ + c)*(N_*N_);
  #pragma unroll
  for (int mm=0;mm<4;mm++)
    #pragma unroll
    for (int nn=0;nn<4;nn++)
      Sp[(ty*4+mm)*N_ + tx*4+nn] = acc[mm][nn];
}

// ---------------- sequential prefix over chunks ----------------
__global__ __launch_bounds__(256) void wkv_prefix(float* __restrict__ S, const u16* __restrict__ td){
  const int bh = blockIdx.x, h = bh&7;
  const float wdec = expf(-expf(bf2f(td[h])));
  const float wsd = powf(wdec, (float)Q_);
  float* Sp = S + (size_t)bh*NC_*N_*N_;
  for (int e=threadIdx.x; e<N_*N_; e+=256){
    float cur = 0.f;
    for (int cc=0;cc<NC_;++cc){
      float sc = Sp[(size_t)cc*N_*N_ + e];
      Sp[(size_t)cc*N_*N_ + e] = cur;
      cur = wsd*cur + sc;
    }
  }
}

// ---------------- inter-chunk: y += (r @ state_c) * wdec^i ----------------
__global__ __launch_bounds__(256) void wkv_inter(const u16* __restrict__ Rb, const float* __restrict__ S,
    const u16* __restrict__ td, float* __restrict__ y){
  __shared__ float st[64][65];
  __shared__ float rs[64][68];
  __shared__ float wpow[Q_];
  const int c = blockIdx.x>>2, ip = blockIdx.x&3;
  const int bh = blockIdx.y, b = bh>>3, h = bh&7;
  const int tid = threadIdx.x, tx = tid&15, ty = tid>>4;
  const float wdec = expf(-expf(bf2f(td[h])));
  wpow[tid] = powf(wdec, (float)tid);
  const float* Sp = S + ((size_t)bh*NC_ + c)*(N_*N_);
  for (int e=tid;e<N_*N_;e+=256) st[e>>6][e&63] = Sp[e];
  const size_t base = ((size_t)b*T_ + (size_t)c*Q_)*C_ + h*N_;
  const int i0 = ip*64;
  {
    const int rr = tid >> 6, cc2 = tid & 63;
    for (int it=0;it<16;++it){ int i=it*4+rr; rs[i][cc2]=bf2f(Rb[base+(size_t)(i0+i)*C_+cc2]); }
  }
  __syncthreads();
  float acc[4][4] = {};
  for (int kk=0;kk<N_;++kk){
    float rv[4], sv[4];
    #pragma unroll
    for (int ii=0;ii<4;ii++) rv[ii]=rs[ty*4+ii][kk];
    #pragma unroll
    for (int nn=0;nn<4;nn++) sv[nn]=st[kk][tx*4+nn];
    #pragma unroll
    for (int ii=0;ii<4;ii++)
      #pragma unroll
      for (int nn=0;nn<4;nn++) acc[ii][nn]+=rv[ii]*sv[nn];
  }
  #pragma unroll
  for (int ii=0;ii<4;ii++){
    int il = i0+ty*4+ii;
    #pragma unroll
    for (int nn=0;nn<4;nn++)
      y[base + (size_t)il*C_ + tx*4+nn] += wpow[il]*acc[ii][nn];
  }
}

// ---------------- GroupNorm over head dim + *silu(g), bf16 out ----------------
__global__ __launch_bounds__(64) void gn_kernel(const float* __restrict__ y, const u16* __restrict__ gnw,
    const u16* __restrict__ gnb, const u16* __restrict__ g, u16* __restrict__ out){
  const int id = blockIdx.x;           // (b*T_+t)*H_ + h
  const int h = id & 7;
  const size_t rowc = (size_t)(id >> 3);
  const int lane = threadIdx.x;
  const size_t off = rowc*C_ + h*N_ + lane;
  float v = y[off];
  float s = v, ss = v*v;
  #pragma unroll
  for (int o=32;o>0;o>>=1){ s+=__shfl_xor(s,o,64); ss+=__shfl_xor(ss,o,64); }
  float mu = s*(1.f/N_);
  float var = ss*(1.f/N_) - mu*mu;
  float inv = rsqrtf(fmaxf(var,0.f) + 6.4e-4f);   // GN_EPS = 1e-5*64
  int ci = h*N_+lane;
  float gg = bf2f(g[off]);
  float sil = gg/(1.f+expf(-gg));
  out[off] = f2bf(((v-mu)*inv*bf2f(gnw[ci]) + bf2f(gnb[ci]))*sil);
}

// ---------------- channel-mix tail: x += sigmoid(rr) * hv ----------------
__global__ __launch_bounds__(256) void cmix_fuse(const float* __restrict__ rr,
    const float* __restrict__ hv, float* __restrict__ x){
  size_t i = (size_t)blockIdx.x*256 + threadIdx.x;
  float r = rr[i];
  x[i] += hv[i]/(1.f+expf(-r));
}

// ---------------- logits for last position: [B,V] = xf @ wte^T ----------------
__global__ __launch_bounds__(256) void logits_kernel(const float* __restrict__ xf,
    const u16* __restrict__ wte, void* __restrict__ out, const int* __restrict__ flag){
  const int wid = threadIdx.x>>6, lane = threadIdx.x&63;
  const int gw = blockIdx.x*4 + wid;     // 0 .. B*V-1
  const int b = gw / V_, v = gw - b*V_;
  const u16* wrow = wte + (size_t)v*C_;
  const float* xr = xf + b*C_;
  union {uint4 q; u16 h[8];} uu;
  uu.q = *(const uint4*)(wrow + lane*8);
  float s = 0.f;
  #pragma unroll
  for (int j=0;j<8;j++) s += bf2f(uu.h[j])*xr[lane*8+j];
  #pragma unroll
  for (int o=32;o>0;o>>=1) s += __shfl_down(s,o,64);
  if (lane==0){
    size_t o = (size_t)b*V_ + v;
    if (*flag) ((float*)out)[o] = s;          // fp32 harness
    else       ((u16*)out)[o]   = f2bf(s);    // bf16 harness
  }
}

extern "C" void kernel_launch(void* const* d_in, const int* in_sizes, int n_in,
                              void* d_out, int out_size, void* d_ws, size_t ws_size,
                              hipStream_t stream){
  (void)out_size; (void)ws_size;
  const int* idx  = (const int*)d_in[0];

  char* ws = (char*)d_ws;
  const size_t MC  = (size_t)M_*C_;
  // ---- workspace layout (bytes) ----
  size_t o = 0;
  int* flag = (int*)(ws + o);            o += 1024;
  float* X   = (float*)(ws + o);         o += MC*4;            // fp32 residual
  float* XLN = (float*)(ws + o);         o += MC*4;            // also Y / HV
  float* Y  = XLN;  float* HV = XLN;
  u16* MK = (u16*)(ws + o);              o += MC*2;            // also YGN
  u16* MV = (u16*)(ws + o);              o += MC*2;
  u16* MR = (u16*)(ws + o);              o += MC*2;            // also S (tmix) / RR (cmix)
  u16* MG = (u16*)(ws + o);              o += MC*2;
  u16* Rb = (u16*)(ws + o);              o += MC*2;            // H1 spans Rb..Vb
  u16* Kb = (u16*)(ws + o);              o += MC*2;
  u16* Vb = (u16*)(ws + o);              o += MC*2;
  u16* Gb = (u16*)(ws + o);              o += MC*2;
  float* XF = (float*)(ws + o);          o += 65536;
  u16* pool = (u16*)(ws + o);            // canonical bf16 inputs
  u16* YGN = MK;
  float* S  = (float*)MR;    // live only during tmix phase
  u16* H1 = Rb;              // [M,3C] bf16, spans Rb..Vb
  float* RR = (float*)MR;    // [M,C] f32, spans MR..MG — disjoint from H1 (race fix)

  // ---- dtype detect + canonicalize all non-integer inputs ----
  detect_kernel<<<1,256,0,stream>>>(d_in[12], flag);   // probe Wr
  u16* cw[24];
  {
    size_t poff = 0;
    for (int i=1;i<24;i++){ cw[i] = pool + poff; poff += (size_t)in_sizes[i]; }
  }
  for (int i=1;i<24;i++){
    int n = in_sizes[i];
    int blocks = (n + 255)/256; if (blocks > 4096) blocks = 4096;
    convert_kernel<<<blocks,256,0,stream>>>(d_in[i], cw[i], n, flag);
  }
  const u16* wte  = cw[1];  const u16* wpe  = cw[2];
  const u16* ln1w = cw[3];  const u16* ln2w = cw[4];  const u16* lnfw = cw[5];
  const u16* maak = cw[6];  const u16* maav = cw[7];
  const u16* maar = cw[8];  const u16* maag = cw[9];
  const u16* tdec = cw[10]; const u16* tfir = cw[11];
  const u16* Wr   = cw[12]; const u16* Wk   = cw[13]; const u16* Wv   = cw[14];
  const u16* Wg   = cw[15]; const u16* Wo   = cw[16];
  const u16* gnw  = cw[17]; const u16* gnb  = cw[18];
  const u16* cmk  = cw[19]; const u16* cmr  = cw[20];
  const u16* Wck  = cw[21]; const u16* Wcv  = cw[22]; const u16* Wcr  = cw[23];

  embed_kernel<<<M_,256,0,stream>>>(idx,wte,wpe,X);
  dim3 gsq(C_/128, M_/128);        // (4,64)
  dim3 g4 (C_/128, M_/128, 4);     // fused projections
  dim3 g2 (C_/128, M_/128, 2);     // fused cmix v/r
  dim3 gck(3*C_/128, M_/128);      // (12,64)
  for (int l=0;l<L_;++l){
    // ---- time mix ----
    ln_kernel<<<M_,256,0,stream>>>(X, ln1w+l*C_, XLN, 1e-5f);
    tmix_mix_kernel<<<M_,256,0,stream>>>(XLN, maak+l*C_, maav+l*C_, maar+l*C_, maag+l*C_,
                                         MK,MV,MR,MG);
    gemm4_mfma<<<g4,256,0,stream>>>(MK, Wr+(size_t)l*C_*C_, Wk+(size_t)l*C_*C_,
                                    Wv+(size_t)l*C_*C_, Wg+(size_t)l*C_*C_, Rb);
    wkv_intra<<<dim3(NC_*4, B_*H_),256,0,stream>>>(Rb,Kb,Vb, tdec+l*H_, tfir+l*H_, Y);
    wkv_state<<<dim3(NC_,   B_*H_),256,0,stream>>>(Kb,Vb, tdec+l*H_, S);
    wkv_prefix<<<B_*H_,256,0,stream>>>(S, tdec+l*H_);
    wkv_inter<<<dim3(NC_*4, B_*H_),256,0,stream>>>(Rb, S, tdec+l*H_, Y);
    gn_kernel<<<M_*H_,64,0,stream>>>(Y, gnw+l*C_, gnb+l*C_, Gb, YGN);
    gemm_mfma<ACT_ADD_F32><<<gsq,256,0,stream>>>(YGN, Wo+(size_t)l*C_*C_, X, nullptr, C_, C_);
    // ---- channel mix ----
    ln_kernel<<<M_,256,0,stream>>>(X, ln2w+l*C_, XLN, 1e-5f);
    cmix_mix_kernel<<<M_,256,0,stream>>>(XLN, cmk+l*C_, cmr+l*C_, MK, MV);
    gemm_mfma<ACT_RELU2_BF16><<<gck,256,0,stream>>>(MK, Wck+(size_t)l*3*C_*C_, nullptr, H1, 3*C_, C_);
    gemm2_mfma<<<g2,256,0,stream>>>(H1, Wcv+(size_t)l*C_*3*C_, MV, Wcr+(size_t)l*C_*C_, HV, RR);
    cmix_fuse<<<(M_*C_)/256,256,0,stream>>>(RR, HV, X);
  }
  lnf_last<<<B_,256,0,stream>>>(X, lnfw, XF);
  logits_kernel<<<(B_*V_)/4,256,0,stream>>>(XF, wte, d_out, flag);
}

// Round 5
// 1941.435 us; speedup vs baseline: 4.1028x; 1.1244x over previous
//
#include <hip/hip_runtime.h>

#define L_ 6
#define H_ 8
#define C_ 512
#define V_ 32000
#define B_ 2
#define T_ 4096
#define Q_ 256
#define N_ 64
#define NC_ 16
#define M_ 8192   // B*T

typedef unsigned short u16;
typedef __attribute__((ext_vector_type(8))) short bf16x8;
typedef __attribute__((ext_vector_type(4))) float f32x4;

__device__ __forceinline__ float bf2f(u16 u){
  return __uint_as_float(((unsigned int)u) << 16);
}
__device__ __forceinline__ u16 f2bf(float f){
  unsigned int x = __float_as_uint(f);
  return (u16)((x + 0x7fffu + ((x >> 16) & 1u)) >> 16);
}

__device__ __forceinline__ void gl_lds16(const u16* g, u16* l){
  __builtin_amdgcn_global_load_lds((const __attribute__((address_space(1))) void*)g,
                                   (__attribute__((address_space(3))) void*)l, 16, 0, 0);
}

// ---------------- dtype detection: bf16 weights never have |x|>=2 ----------------
__global__ __launch_bounds__(256) void detect_kernel(const void* __restrict__ probe,
                                                     int* __restrict__ flag){
  __shared__ int cnt;
  if (threadIdx.x == 0) cnt = 0;
  __syncthreads();
  const u16* p = (const u16*)probe;
  int c = 0;
  for (int i = threadIdx.x; i < 2048; i += 256){
    int e = (p[i] >> 7) & 0xFF;
    if (e >= 128) c++;
  }
  atomicAdd(&cnt, c);
  __syncthreads();
  if (threadIdx.x == 0) *flag = (cnt > 32) ? 1 : 0;  // 1 = inputs are fp32
}

// ---------------- canonicalize any input to bf16 ----------------
__global__ __launch_bounds__(256) void convert_kernel(const void* __restrict__ src,
    u16* __restrict__ dst, int n, const int* __restrict__ flag){
  const bool f32 = (*flag != 0);
  int stride = gridDim.x * 256;
  for (int i = blockIdx.x*256 + threadIdx.x; i < n; i += stride){
    dst[i] = f32 ? f2bf(((const float*)src)[i]) : ((const u16*)src)[i];
  }
}

// ---------------- embedding: x = wte[idx] + wpe ----------------
__global__ __launch_bounds__(256) void embed_kernel(const int* __restrict__ idx,
    const u16* __restrict__ wte, const u16* __restrict__ wpe, float* __restrict__ x){
  int row = blockIdx.x;                 // b*T + t
  int t = row & (T_-1);
  int tok = idx[row];
  const u16* we = wte + (size_t)tok * C_;
  const u16* wp = wpe + (size_t)t * C_;
  float* xo = x + (size_t)row * C_;
  int c = threadIdx.x;
  xo[c]     = bf2f(we[c])     + bf2f(wp[c]);
  xo[c+256] = bf2f(we[c+256]) + bf2f(wp[c+256]);
}

// ---------------- LayerNorm (no bias), row = one (b,t) ----------------
__global__ __launch_bounds__(256) void ln_kernel(const float* __restrict__ x,
    const u16* __restrict__ w, float* __restrict__ out, float eps){
  int row = blockIdx.x;
  const float* xr = x + (size_t)row*C_;
  float* orow = out + (size_t)row*C_;
  int c = threadIdx.x;
  float v0 = xr[c], v1 = xr[c+256];
  float s = v0+v1, ss = v0*v0+v1*v1;
  int lane = c & 63, wid = c >> 6;
  #pragma unroll
  for (int o=32;o>0;o>>=1){ s += __shfl_down(s,o,64); ss += __shfl_down(ss,o,64); }
  __shared__ float r1[4], r2[4];
  if (lane==0){ r1[wid]=s; r2[wid]=ss; }
  __syncthreads();
  if (c==0){
    float a=r1[0]+r1[1]+r1[2]+r1[3], bq=r2[0]+r2[1]+r2[2]+r2[3];
    float mu = a*(1.f/C_);
    float var = bq*(1.f/C_) - mu*mu;
    r1[0]=mu; r2[0]=rsqrtf(fmaxf(var,0.f)+eps);
  }
  __syncthreads();
  float mu=r1[0], inv=r2[0];
  orow[c]     = (v0-mu)*inv*bf2f(w[c]);
  orow[c+256] = (v1-mu)*inv*bf2f(w[c+256]);
}

// ---------------- final LN for last position only ----------------
__global__ __launch_bounds__(256) void lnf_last(const float* __restrict__ x,
    const u16* __restrict__ w, float* __restrict__ xf){
  int b = blockIdx.x;
  const float* xr = x + ((size_t)b*T_ + (T_-1))*C_;
  int c = threadIdx.x;
  float v0 = xr[c], v1 = xr[c+256];
  float s = v0+v1, ss = v0*v0+v1*v1;
  int lane = c & 63, wid = c >> 6;
  #pragma unroll
  for (int o=32;o>0;o>>=1){ s += __shfl_down(s,o,64); ss += __shfl_down(ss,o,64); }
  __shared__ float r1[4], r2[4];
  if (lane==0){ r1[wid]=s; r2[wid]=ss; }
  __syncthreads();
  if (c==0){
    float a=r1[0]+r1[1]+r1[2]+r1[3], bq=r2[0]+r2[1]+r2[2]+r2[3];
    float mu = a*(1.f/C_);
    float var = bq*(1.f/C_) - mu*mu;
    r1[0]=mu; r2[0]=rsqrtf(fmaxf(var,0.f)+1e-5f);
  }
  __syncthreads();
  float mu=r1[0], inv=r2[0];
  xf[b*C_+c]     = (v0-mu)*inv*bf2f(w[c]);
  xf[b*C_+c+256] = (v1-mu)*inv*bf2f(w[c+256]);
}

// ---------------- time-mix token shift: 4 outputs ----------------
__global__ __launch_bounds__(256) void tmix_mix_kernel(const float* __restrict__ xln,
    const u16* __restrict__ mk, const u16* __restrict__ mv,
    const u16* __restrict__ mr, const u16* __restrict__ mg,
    u16* __restrict__ xk, u16* __restrict__ xv, u16* __restrict__ xr, u16* __restrict__ xg){
  int row = blockIdx.x; int t = row & (T_-1);
  size_t off = (size_t)row*C_;
  const float* cur = xln + off;
  #pragma unroll
  for (int p=0;p<2;p++){
    int c = threadIdx.x + p*256;
    float xc = cur[c];
    float xp = t ? cur[c - C_] : 0.f;   // previous token (same batch), zero at t=0
    float xx = xp - xc;
    xk[off+c] = f2bf(xc + xx*bf2f(mk[c]));
    xv[off+c] = f2bf(xc + xx*bf2f(mv[c]));
    xr[off+c] = f2bf(xc + xx*bf2f(mr[c]));
    xg[off+c] = f2bf(xc + xx*bf2f(mg[c]));
  }
}

// ---------------- channel-mix token shift: 2 outputs ----------------
__global__ __launch_bounds__(256) void cmix_mix_kernel(const float* __restrict__ xln,
    const u16* __restrict__ mk, const u16* __restrict__ mr,
    u16* __restrict__ xk, u16* __restrict__ xr){
  int row = blockIdx.x; int t = row & (T_-1);
  size_t off = (size_t)row*C_;
  const float* cur = xln + off;
  #pragma unroll
  for (int p=0;p<2;p++){
    int c = threadIdx.x + p*256;
    float xc = cur[c];
    float xp = t ? cur[c - C_] : 0.f;
    float xx = xp - xc;
    xk[off+c] = f2bf(xc + xx*bf2f(mk[c]));
    xr[off+c] = f2bf(xc + xx*bf2f(mr[c]));
  }
}

// ================= MFMA GEMM: Y[M,N] = X[M,K] @ W[N,K]^T =================
#define ACT_F32 0
#define ACT_RELU2_BF16 1
#define ACT_ADD_F32 2
#define ACT_BF16 3

template<int ACT>
__device__ __forceinline__ void gemm_mfma_body(const u16* __restrict__ X, const u16* __restrict__ W,
    float* __restrict__ Yf, u16* __restrict__ Yb, int Ndim, int Kdim, int bm, int bn){
  __shared__ __align__(16) u16 Al[128*64];
  __shared__ __align__(16) u16 Bl[128*64];
  const int tid = threadIdx.x;
  const int wv = tid >> 6, ln = tid & 63;
  const int m16 = ln & 15, q = ln >> 4;
  const int wm = (wv & 1)*64, wn = (wv >> 1)*64;

  f32x4 acc[4][4];
  #pragma unroll
  for (int i=0;i<4;i++)
    #pragma unroll
    for (int j=0;j<4;j++) acc[i][j] = f32x4{0.f,0.f,0.f,0.f};

  const int r0 = wv*8 + (ln >> 3);
  const int c0 = (ln & 7)*8;
  const u16* ga = X + (size_t)(bm + r0)*Kdim + c0;
  const u16* gb = W + (size_t)(bn + r0)*Kdim + c0;
  u16* la = Al + r0*64 + c0;
  u16* lb = Bl + r0*64 + c0;

  for (int k0=0; k0<Kdim; k0+=64){
    #pragma unroll
    for (int s=0;s<4;s++){
      gl_lds16(ga + (size_t)(s*32)*Kdim + k0, la + s*2048);
      gl_lds16(gb + (size_t)(s*32)*Kdim + k0, lb + s*2048);
    }
    __syncthreads();
    #pragma unroll
    for (int kh=0; kh<2; kh++){
      bf16x8 af[4], bfr[4];
      #pragma unroll
      for (int i=0;i<4;i++) af[i]  = *(const bf16x8*)(Al + (wm + i*16 + m16)*64 + kh*32 + q*8);
      #pragma unroll
      for (int j=0;j<4;j++) bfr[j] = *(const bf16x8*)(Bl + (wn + j*16 + m16)*64 + kh*32 + q*8);
      #pragma unroll
      for (int i=0;i<4;i++)
        #pragma unroll
        for (int j=0;j<4;j++)
          acc[i][j] = __builtin_amdgcn_mfma_f32_16x16x32_bf16(af[i], bfr[j], acc[i][j], 0, 0, 0);
    }
    __syncthreads();
  }

  #pragma unroll
  for (int i=0;i<4;i++){
    int row = bm + wm + i*16 + q*4;
    #pragma unroll
    for (int j=0;j<4;j++){
      int col = bn + wn + j*16 + m16;
      #pragma unroll
      for (int r=0;r<4;r++){
        size_t off = (size_t)(row + r)*Ndim + col;
        float v = acc[i][j][r];
        if (ACT==ACT_F32) Yf[off] = v;
        else if (ACT==ACT_RELU2_BF16){ float rr = v>0.f ? v : 0.f; Yb[off] = f2bf(rr*rr); }
        else if (ACT==ACT_BF16) Yb[off] = f2bf(v);
        else Yf[off] += v;
      }
    }
  }
}

template<int ACT>
__global__ __launch_bounds__(256,2) void gemm_mfma(const u16* __restrict__ X, const u16* __restrict__ W,
    float* __restrict__ Yf, u16* __restrict__ Yb, int Ndim, int Kdim){
  gemm_mfma_body<ACT>(X, W, Yf, Yb, Ndim, Kdim, blockIdx.y*128, blockIdx.x*128);
}

// fused r/k/v/g projections
__global__ __launch_bounds__(256,2) void gemm4_mfma(const u16* __restrict__ Abase,
    const u16* __restrict__ W0, const u16* __restrict__ W1,
    const u16* __restrict__ W2, const u16* __restrict__ W3,
    u16* __restrict__ Obase){
  const size_t MC = (size_t)M_*C_;
  const int z = blockIdx.z;
  const u16* X; const u16* W;
  switch (z){
    case 0:  X = Abase + 2*MC; W = W0; break;   // Rb <- MR @ Wr
    case 1:  X = Abase;        W = W1; break;   // Kb <- MK @ Wk
    case 2:  X = Abase + 1*MC; W = W2; break;   // Vb <- MV @ Wv
    default: X = Abase + 3*MC; W = W3; break;   // Gb <- MG @ Wg
  }
  gemm_mfma_body<ACT_BF16>(X, W, nullptr, Obase + (size_t)z*MC, C_, C_,
                           blockIdx.y*128, blockIdx.x*128);
}

// fused cmix value+receptance GEMMs (RR must NOT alias H1)
__global__ __launch_bounds__(256,2) void gemm2_mfma(const u16* __restrict__ H1, const u16* __restrict__ Wcv,
    const u16* __restrict__ MV, const u16* __restrict__ Wcr,
    float* __restrict__ HV, float* __restrict__ RR){
  if (blockIdx.z == 0)
    gemm_mfma_body<ACT_F32>(H1, Wcv, HV, nullptr, C_, 3*C_, blockIdx.y*128, blockIdx.x*128);
  else
    gemm_mfma_body<ACT_F32>(MV, Wcr, RR, nullptr, C_, C_, blockIdx.y*128, blockIdx.x*128);
}

// ---------------- per-(b,h) transpose: Vt[(bh)*64+n][t] = Vb[(b*T+t)*C + h*64+n] ----------------
// XOR-swizzled LDS tile: element (t,n) stored at col n ^ (((t>>3)&7)<<3). Reads/writes hit
// all 32 banks 2-way (free); both global sides fully coalesced (16B).
__global__ __launch_bounds__(256) void vt_transpose(const u16* __restrict__ Vb, u16* __restrict__ Vt){
  __shared__ __align__(16) u16 tile[64*64];
  const int t0 = blockIdx.x*64, bh = blockIdx.y, b = bh>>3, h = bh&7;
  const int tid = threadIdx.x;
  #pragma unroll
  for (int it=0; it<2; ++it){
    int tl = it*32 + (tid>>3);
    int n0 = (tid&7)*8;
    uint4 v = *(const uint4*)(Vb + ((size_t)(b*T_ + t0 + tl))*C_ + h*N_ + n0);
    int col = n0 ^ (((tl>>3)&7)<<3);
    *(uint4*)&tile[tl*64 + col] = v;
  }
  __syncthreads();
  #pragma unroll
  for (int it=0; it<2; ++it){
    int nl = it*32 + (tid>>3);
    int t0l = (tid&7)*8;
    int swz = (tid&7)<<3;           // ((t0l+e)>>3)&7 == tid&7 for e<8
    union {uint4 q; u16 h2[8];} pk;
    #pragma unroll
    for (int e=0;e<8;++e)
      pk.h2[e] = tile[(t0l+e)*64 + (nl ^ swz)];
    *(uint4*)(Vt + ((size_t)(bh*N_ + nl))*T_ + t0 + t0l) = pk.q;
  }
}

// ---------------- WKV intra-chunk, MFMA: y = ((r@k^T) * Wmat) @ v ----------------
// grid (NC*4, B*H); 4 waves; wave wv owns 16 rows (iw0..iw0+15) of its block's 64 rows.
// Causal: strips jt>ip are zero -> skipped. A/B frags of r@k^T load straight from global
// (both are row segments). P round-trips through per-wave LDS (C-layout -> A-layout).
// P@v's B-operand reads Vt rows (v^T) straight from global.
__global__ __launch_bounds__(256) void wkv_intra_mfma(const u16* __restrict__ Rb,
    const u16* __restrict__ Kb, const u16* __restrict__ Vt,
    const u16* __restrict__ td, const u16* __restrict__ tf, float* __restrict__ y){
  __shared__ float wpow[Q_];
  __shared__ __align__(16) u16 P[4][16][72];   // per-wave P strip, 144B rows (16B aligned)
  const int c = blockIdx.x >> 2, ip = blockIdx.x & 3;
  const int bh = blockIdx.y, b = bh >> 3, h = bh & 7;
  const int tid = threadIdx.x, wv = tid >> 6, ln = tid & 63;
  const int m16 = ln & 15, q = ln >> 4;
  const float wdec = expf(-expf(bf2f(td[h])));
  const float uu = bf2f(tf[h]);
  wpow[tid] = powf(wdec, (float)tid);
  __syncthreads();
  const size_t base = ((size_t)b*T_ + (size_t)c*Q_)*C_ + h*N_;
  const int iw0 = ip*64 + wv*16;               // chunk-local first row of this wave
  const u16* rrow = Rb + base + (size_t)(iw0 + m16)*C_;
  bf16x8 af0 = *(const bf16x8*)(rrow + q*8);        // A-frags of r (K=64 -> 2)
  bf16x8 af1 = *(const bf16x8*)(rrow + 32 + q*8);
  f32x4 acc[4];
  #pragma unroll
  for (int nt=0;nt<4;++nt) acc[nt] = f32x4{0.f,0.f,0.f,0.f};
  const int irow = iw0 + q*4;                  // chunk-local row of acc element r
  const u16* vtb = Vt + (size_t)(bh*N_)*T_ + (size_t)c*Q_;
  for (int jt=0; jt<=ip; ++jt){
    f32x4 s[4];
    #pragma unroll
    for (int j2=0;j2<4;++j2) s[j2] = f32x4{0.f,0.f,0.f,0.f};
    #pragma unroll
    for (int j2=0;j2<4;++j2){
      const u16* kr = Kb + base + (size_t)(jt*64 + j2*16 + m16)*C_;
      bf16x8 b0 = *(const bf16x8*)(kr + q*8);
      bf16x8 b1 = *(const bf16x8*)(kr + 32 + q*8);
      s[j2] = __builtin_amdgcn_mfma_f32_16x16x32_bf16(af0, b0, s[j2], 0,0,0);
      s[j2] = __builtin_amdgcn_mfma_f32_16x16x32_bf16(af1, b1, s[j2], 0,0,0);
    }
    // decay/bonus mask, bf16, store P in row-major [i][j] (A-layout for matmul2)
    #pragma unroll
    for (int j2=0;j2<4;++j2){
      int jc = jt*64 + j2*16 + m16;
      #pragma unroll
      for (int r=0;r<4;++r){
        int ic = irow + r;
        float w = (jc < ic) ? wpow[ic-jc-1] : ((jc==ic) ? uu : 0.f);
        P[wv][q*4+r][j2*16+m16] = f2bf(s[j2][r]*w);
      }
    }
    __asm__ volatile("s_waitcnt lgkmcnt(0)" ::: "memory");  // P visible wave-wide (no cross-wave use)
    #pragma unroll
    for (int kp=0;kp<2;++kp){
      bf16x8 ap = *(const bf16x8*)&P[wv][m16][kp*32 + q*8];
      #pragma unroll
      for (int nt=0;nt<4;++nt){
        bf16x8 bv = *(const bf16x8*)(vtb + (size_t)(nt*16 + m16)*T_ + jt*64 + kp*32 + q*8);
        acc[nt] = __builtin_amdgcn_mfma_f32_16x16x32_bf16(ap, bv, acc[nt], 0,0,0);
      }
    }
  }
  #pragma unroll
  for (int nt=0;nt<4;++nt)
    #pragma unroll
    for (int r=0;r<4;++r)
      y[base + (size_t)(irow + r)*C_ + nt*16 + m16] = acc[nt][r];
}

// ---------------- per-chunk state contribution S_c = (k*wkv)^T @ v (VALU, f32) ----------------
__global__ __launch_bounds__(256) void wkv_state(const u16* __restrict__ Kb, const u16* __restrict__ Vb,
    const u16* __restrict__ td, float* __restrict__ S){
  __shared__ float kst[64][68];
  __shared__ float vst[64][68];
  __shared__ float wpow[Q_];
  const int c = blockIdx.x, bh = blockIdx.y, b = bh>>3, h = bh&7;
  const int tid = threadIdx.x, tx = tid&15, ty = tid>>4;
  const float wdec = expf(-expf(bf2f(td[h])));
  wpow[tid] = powf(wdec, (float)tid);
  const size_t base = ((size_t)b*T_ + (size_t)c*Q_)*C_ + h*N_;
  float acc[4][4] = {};
  for (int jt=0;jt<4;++jt){
    __syncthreads();
    {
      const int rr = tid >> 6, cc2 = tid & 63;
      const int j0 = jt*64;
      for (int it=0; it<16; ++it){
        int j = it*4 + rr;
        kst[j][cc2] = bf2f(Kb[base + (size_t)(j0+j)*C_ + cc2]);
        vst[j][cc2] = bf2f(Vb[base + (size_t)(j0+j)*C_ + cc2]);
      }
    }
    __syncthreads();
    for (int jl=0;jl<64;++jl){
      float f = wpow[Q_-1-(jt*64+jl)];
      float kv[4], vv[4];
      #pragma unroll
      for (int mm=0;mm<4;mm++) kv[mm]=kst[jl][ty*4+mm]*f;
      #pragma unroll
      for (int nn=0;nn<4;nn++) vv[nn]=vst[jl][tx*4+nn];
      #pragma unroll
      for (int mm=0;mm<4;mm++)
        #pragma unroll
        for (int nn=0;nn<4;nn++) acc[mm][nn]+=kv[mm]*vv[nn];
    }
  }
  float* Sp = S + ((size_t)bh*NC_ + c)*(N_*N_);
  #pragma unroll
  for (int mm=0;mm<4;mm++)
    #pragma unroll
    for (int nn=0;nn<4;nn++)
      Sp[(ty*4+mm)*N_ + tx*4+nn] = acc[mm][nn];
}

// ---------------- sequential prefix over chunks ----------------
__global__ __launch_bounds__(256) void wkv_prefix(float* __restrict__ S, const u16* __restrict__ td){
  const int bh = blockIdx.x, h = bh&7;
  const float wdec = expf(-expf(bf2f(td[h])));
  const float wsd = powf(wdec, (float)Q_);
  float* Sp = S + (size_t)bh*NC_*N_*N_;
  for (int e=threadIdx.x; e<N_*N_; e+=256){
    float cur = 0.f;
    for (int cc=0;cc<NC_;++cc){
      float sc = Sp[(size_t)cc*N_*N_ + e];
      Sp[(size_t)cc*N_*N_ + e] = cur;
      cur = wsd*cur + sc;
    }
  }
}

// ---------------- inter-chunk: y += (r @ state_c) * wdec^i (VALU, f32) ----------------
__global__ __launch_bounds__(256) void wkv_inter(const u16* __restrict__ Rb, const float* __restrict__ S,
    const u16* __restrict__ td, float* __restrict__ y){
  __shared__ float st[64][65];
  __shared__ float rs[64][68];
  __shared__ float wpow[Q_];
  const int c = blockIdx.x>>2, ip = blockIdx.x&3;
  const int bh = blockIdx.y, b = bh>>3, h = bh&7;
  const int tid = threadIdx.x, tx = tid&15, ty = tid>>4;
  const float wdec = expf(-expf(bf2f(td[h])));
  wpow[tid] = powf(wdec, (float)tid);
  const float* Sp = S + ((size_t)bh*NC_ + c)*(N_*N_);
  for (int e=tid;e<N_*N_;e+=256) st[e>>6][e&63] = Sp[e];
  const size_t base = ((size_t)b*T_ + (size_t)c*Q_)*C_ + h*N_;
  const int i0 = ip*64;
  {
    const int rr = tid >> 6, cc2 = tid & 63;
    for (int it=0;it<16;++it){ int i=it*4+rr; rs[i][cc2]=bf2f(Rb[base+(size_t)(i0+i)*C_+cc2]); }
  }
  __syncthreads();
  float acc[4][4] = {};
  for (int kk=0;kk<N_;++kk){
    float rv[4], sv[4];
    #pragma unroll
    for (int ii=0;ii<4;ii++) rv[ii]=rs[ty*4+ii][kk];
    #pragma unroll
    for (int nn=0;nn<4;nn++) sv[nn]=st[kk][tx*4+nn];
    #pragma unroll
    for (int ii=0;ii<4;ii++)
      #pragma unroll
      for (int nn=0;nn<4;nn++) acc[ii][nn]+=rv[ii]*sv[nn];
  }
  #pragma unroll
  for (int ii=0;ii<4;ii++){
    int il = i0+ty*4+ii;
    #pragma unroll
    for (int nn=0;nn<4;nn++)
      y[base + (size_t)il*C_ + tx*4+nn] += wpow[il]*acc[ii][nn];
  }
}

// ---------------- GroupNorm over head dim + *silu(g), bf16 out ----------------
__global__ __launch_bounds__(64) void gn_kernel(const float* __restrict__ y, const u16* __restrict__ gnw,
    const u16* __restrict__ gnb, const u16* __restrict__ g, u16* __restrict__ out){
  const int id = blockIdx.x;           // (b*T_+t)*H_ + h
  const int h = id & 7;
  const size_t rowc = (size_t)(id >> 3);
  const int lane = threadIdx.x;
  const size_t off = rowc*C_ + h*N_ + lane;
  float v = y[off];
  float s = v, ss = v*v;
  #pragma unroll
  for (int o=32;o>0;o>>=1){ s+=__shfl_xor(s,o,64); ss+=__shfl_xor(ss,o,64); }
  float mu = s*(1.f/N_);
  float var = ss*(1.f/N_) - mu*mu;
  float inv = rsqrtf(fmaxf(var,0.f) + 6.4e-4f);   // GN_EPS = 1e-5*64
  int ci = h*N_+lane;
  float gg = bf2f(g[off]);
  float sil = gg/(1.f+expf(-gg));
  out[off] = f2bf(((v-mu)*inv*bf2f(gnw[ci]) + bf2f(gnb[ci]))*sil);
}

// ---------------- channel-mix tail: x += sigmoid(rr) * hv ----------------
__global__ __launch_bounds__(256) void cmix_fuse(const float* __restrict__ rr,
    const float* __restrict__ hv, float* __restrict__ x){
  size_t i = (size_t)blockIdx.x*256 + threadIdx.x;
  float r = rr[i];
  x[i] += hv[i]/(1.f+expf(-r));
}

// ---------------- logits for last position: [B,V] = xf @ wte^T ----------------
__global__ __launch_bounds__(256) void logits_kernel(const float* __restrict__ xf,
    const u16* __restrict__ wte, void* __restrict__ out, const int* __restrict__ flag){
  const int wid = threadIdx.x>>6, lane = threadIdx.x&63;
  const int gw = blockIdx.x*4 + wid;     // 0 .. B*V-1
  const int b = gw / V_, v = gw - b*V_;
  const u16* wrow = wte + (size_t)v*C_;
  const float* xr = xf + b*C_;
  union {uint4 q; u16 h[8];} uu;
  uu.q = *(const uint4*)(wrow + lane*8);
  float s = 0.f;
  #pragma unroll
  for (int j=0;j<8;j++) s += bf2f(uu.h[j])*xr[lane*8+j];
  #pragma unroll
  for (int o=32;o>0;o>>=1) s += __shfl_down(s,o,64);
  if (lane==0){
    size_t o = (size_t)b*V_ + v;
    if (*flag) ((float*)out)[o] = s;          // fp32 harness
    else       ((u16*)out)[o]   = f2bf(s);    // bf16 harness
  }
}

extern "C" void kernel_launch(void* const* d_in, const int* in_sizes, int n_in,
                              void* d_out, int out_size, void* d_ws, size_t ws_size,
                              hipStream_t stream){
  (void)out_size; (void)ws_size;
  const int* idx  = (const int*)d_in[0];

  char* ws = (char*)d_ws;
  const size_t MC  = (size_t)M_*C_;
  // ---- workspace layout (bytes) ----
  size_t o = 0;
  int* flag = (int*)(ws + o);            o += 1024;
  float* X   = (float*)(ws + o);         o += MC*4;            // fp32 residual
  float* XLN = (float*)(ws + o);         o += MC*4;            // also Y / HV
  float* Y  = XLN;  float* HV = XLN;
  u16* MK = (u16*)(ws + o);              o += MC*2;            // also YGN
  u16* MV = (u16*)(ws + o);              o += MC*2;
  u16* MR = (u16*)(ws + o);              o += MC*2;            // also S (tmix) / RR (cmix)
  u16* MG = (u16*)(ws + o);              o += MC*2;
  u16* Rb = (u16*)(ws + o);              o += MC*2;            // H1 spans Rb..Vb
  u16* Kb = (u16*)(ws + o);              o += MC*2;
  u16* Vb = (u16*)(ws + o);              o += MC*2;
  u16* Gb = (u16*)(ws + o);              o += MC*2;
  u16* Vt = (u16*)(ws + o);              o += MC*2;            // v^T per (b,h): [BH*64, T]
  float* XF = (float*)(ws + o);          o += 65536;
  u16* pool = (u16*)(ws + o);            // canonical bf16 inputs
  u16* YGN = MK;
  float* S  = (float*)MR;    // live only during tmix phase
  u16* H1 = Rb;              // [M,3C] bf16, spans Rb..Vb
  float* RR = (float*)MR;    // [M,C] f32, spans MR..MG — disjoint from H1

  // ---- dtype detect + canonicalize all non-integer inputs ----
  detect_kernel<<<1,256,0,stream>>>(d_in[12], flag);   // probe Wr
  u16* cw[24];
  {
    size_t poff = 0;
    for (int i=1;i<24;i++){ cw[i] = pool + poff; poff += (size_t)in_sizes[i]; }
  }
  for (int i=1;i<24;i++){
    int n = in_sizes[i];
    int blocks = (n + 255)/256; if (blocks > 4096) blocks = 4096;
    convert_kernel<<<blocks,256,0,stream>>>(d_in[i], cw[i], n, flag);
  }
  const u16* wte  = cw[1];  const u16* wpe  = cw[2];
  const u16* ln1w = cw[3];  const u16* ln2w = cw[4];  const u16* lnfw = cw[5];
  const u16* maak = cw[6];  const u16* maav = cw[7];
  const u16* maar = cw[8];  const u16* maag = cw[9];
  const u16* tdec = cw[10]; const u16* tfir = cw[11];
  const u16* Wr   = cw[12]; const u16* Wk   = cw[13]; const u16* Wv   = cw[14];
  const u16* Wg   = cw[15]; const u16* Wo   = cw[16];
  const u16* gnw  = cw[17]; const u16* gnb  = cw[18];
  const u16* cmk  = cw[19]; const u16* cmr  = cw[20];
  const u16* Wck  = cw[21]; const u16* Wcv  = cw[22]; const u16* Wcr  = cw[23];

  embed_kernel<<<M_,256,0,stream>>>(idx,wte,wpe,X);
  dim3 gsq(C_/128, M_/128);        // (4,64)
  dim3 g4 (C_/128, M_/128, 4);     // fused projections
  dim3 g2 (C_/128, M_/128, 2);     // fused cmix v/r
  dim3 gck(3*C_/128, M_/128);      // (12,64)
  for (int l=0;l<L_;++l){
    // ---- time mix ----
    ln_kernel<<<M_,256,0,stream>>>(X, ln1w+l*C_, XLN, 1e-5f);
    tmix_mix_kernel<<<M_,256,0,stream>>>(XLN, maak+l*C_, maav+l*C_, maar+l*C_, maag+l*C_,
                                         MK,MV,MR,MG);
    gemm4_mfma<<<g4,256,0,stream>>>(MK, Wr+(size_t)l*C_*C_, Wk+(size_t)l*C_*C_,
                                    Wv+(size_t)l*C_*C_, Wg+(size_t)l*C_*C_, Rb);
    vt_transpose<<<dim3(T_/64, B_*H_),256,0,stream>>>(Vb, Vt);
    wkv_intra_mfma<<<dim3(NC_*4, B_*H_),256,0,stream>>>(Rb,Kb,Vt, tdec+l*H_, tfir+l*H_, Y);
    wkv_state<<<dim3(NC_,   B_*H_),256,0,stream>>>(Kb,Vb, tdec+l*H_, S);
    wkv_prefix<<<B_*H_,256,0,stream>>>(S, tdec+l*H_);
    wkv_inter<<<dim3(NC_*4, B_*H_),256,0,stream>>>(Rb, S, tdec+l*H_, Y);
    gn_kernel<<<M_*H_,64,0,stream>>>(Y, gnw+l*C_, gnb+l*C_, Gb, YGN);
    gemm_mfma<ACT_ADD_F32><<<gsq,256,0,stream>>>(YGN, Wo+(size_t)l*C_*C_, X, nullptr, C_, C_);
    // ---- channel mix ----
    ln_kernel<<<M_,256,0,stream>>>(X, ln2w+l*C_, XLN, 1e-5f);
    cmix_mix_kernel<<<M_,256,0,stream>>>(XLN, cmk+l*C_, cmr+l*C_, MK, MV);
    gemm_mfma<ACT_RELU2_BF16><<<gck,256,0,stream>>>(MK, Wck+(size_t)l*3*C_*C_, nullptr, H1, 3*C_, C_);
    gemm2_mfma<<<g2,256,0,stream>>>(H1, Wcv+(size_t)l*C_*3*C_, MV, Wcr+(size_t)l*C_*C_, HV, RR);
    cmix_fuse<<<(M_*C_)/256,256,0,stream>>>(RR, HV, X);
  }
  lnf_last<<<B_,256,0,stream>>>(X, lnfw, XF);
  logits_kernel<<<(B_*V_)/4,256,0,stream>>>(XF, wte, d_out, flag);
}

// Round 6
// 1846.560 us; speedup vs baseline: 4.3136x; 1.0514x over previous
//
#include <hip/hip_runtime.h>

#define L_ 6
#define H_ 8
#define C_ 512
#define V_ 32000
#define B_ 2
#define T_ 4096
#define Q_ 256
#define N_ 64
#define NC_ 16
#define M_ 8192   // B*T

typedef unsigned short u16;
typedef __attribute__((ext_vector_type(8))) short bf16x8;
typedef __attribute__((ext_vector_type(4))) float f32x4;

__device__ __forceinline__ float bf2f(u16 u){
  return __uint_as_float(((unsigned int)u) << 16);
}
__device__ __forceinline__ u16 f2bf(float f){
  unsigned int x = __float_as_uint(f);
  return (u16)((x + 0x7fffu + ((x >> 16) & 1u)) >> 16);
}

__device__ __forceinline__ void gl_lds16(const u16* g, u16* l){
  __builtin_amdgcn_global_load_lds((const __attribute__((address_space(1))) void*)g,
                                   (__attribute__((address_space(3))) void*)l, 16, 0, 0);
}

// ---------------- dtype detection: bf16 weights never have |x|>=2 ----------------
__global__ __launch_bounds__(256) void detect_kernel(const void* __restrict__ probe,
                                                     int* __restrict__ flag){
  __shared__ int cnt;
  if (threadIdx.x == 0) cnt = 0;
  __syncthreads();
  const u16* p = (const u16*)probe;
  int c = 0;
  for (int i = threadIdx.x; i < 2048; i += 256){
    int e = (p[i] >> 7) & 0xFF;
    if (e >= 128) c++;
  }
  atomicAdd(&cnt, c);
  __syncthreads();
  if (threadIdx.x == 0) *flag = (cnt > 32) ? 1 : 0;  // 1 = inputs are fp32
}

// ---------------- canonicalize any input to bf16 ----------------
__global__ __launch_bounds__(256) void convert_kernel(const void* __restrict__ src,
    u16* __restrict__ dst, int n, const int* __restrict__ flag){
  const bool f32 = (*flag != 0);
  int stride = gridDim.x * 256;
  for (int i = blockIdx.x*256 + threadIdx.x; i < n; i += stride){
    dst[i] = f32 ? f2bf(((const float*)src)[i]) : ((const u16*)src)[i];
  }
}

// ---------------- embedding: x = wte[idx] + wpe ----------------
__global__ __launch_bounds__(256) void embed_kernel(const int* __restrict__ idx,
    const u16* __restrict__ wte, const u16* __restrict__ wpe, float* __restrict__ x){
  int row = blockIdx.x;                 // b*T + t
  int t = row & (T_-1);
  int tok = idx[row];
  const u16* we = wte + (size_t)tok * C_;
  const u16* wp = wpe + (size_t)t * C_;
  float* xo = x + (size_t)row * C_;
  int c = threadIdx.x;
  xo[c]     = bf2f(we[c])     + bf2f(wp[c]);
  xo[c+256] = bf2f(we[c+256]) + bf2f(wp[c+256]);
}

// ---------------- LayerNorm (no bias), row = one (b,t) ----------------
__global__ __launch_bounds__(256) void ln_kernel(const float* __restrict__ x,
    const u16* __restrict__ w, float* __restrict__ out, float eps){
  int row = blockIdx.x;
  const float* xr = x + (size_t)row*C_;
  float* orow = out + (size_t)row*C_;
  int c = threadIdx.x;
  float v0 = xr[c], v1 = xr[c+256];
  float s = v0+v1, ss = v0*v0+v1*v1;
  int lane = c & 63, wid = c >> 6;
  #pragma unroll
  for (int o=32;o>0;o>>=1){ s += __shfl_down(s,o,64); ss += __shfl_down(ss,o,64); }
  __shared__ float r1[4], r2[4];
  if (lane==0){ r1[wid]=s; r2[wid]=ss; }
  __syncthreads();
  if (c==0){
    float a=r1[0]+r1[1]+r1[2]+r1[3], bq=r2[0]+r2[1]+r2[2]+r2[3];
    float mu = a*(1.f/C_);
    float var = bq*(1.f/C_) - mu*mu;
    r1[0]=mu; r2[0]=rsqrtf(fmaxf(var,0.f)+eps);
  }
  __syncthreads();
  float mu=r1[0], inv=r2[0];
  orow[c]     = (v0-mu)*inv*bf2f(w[c]);
  orow[c+256] = (v1-mu)*inv*bf2f(w[c+256]);
}

// ---------------- final LN for last position only ----------------
__global__ __launch_bounds__(256) void lnf_last(const float* __restrict__ x,
    const u16* __restrict__ w, float* __restrict__ xf){
  int b = blockIdx.x;
  const float* xr = x + ((size_t)b*T_ + (T_-1))*C_;
  int c = threadIdx.x;
  float v0 = xr[c], v1 = xr[c+256];
  float s = v0+v1, ss = v0*v0+v1*v1;
  int lane = c & 63, wid = c >> 6;
  #pragma unroll
  for (int o=32;o>0;o>>=1){ s += __shfl_down(s,o,64); ss += __shfl_down(ss,o,64); }
  __shared__ float r1[4], r2[4];
  if (lane==0){ r1[wid]=s; r2[wid]=ss; }
  __syncthreads();
  if (c==0){
    float a=r1[0]+r1[1]+r1[2]+r1[3], bq=r2[0]+r2[1]+r2[2]+r2[3];
    float mu = a*(1.f/C_);
    float var = bq*(1.f/C_) - mu*mu;
    r1[0]=mu; r2[0]=rsqrtf(fmaxf(var,0.f)+1e-5f);
  }
  __syncthreads();
  float mu=r1[0], inv=r2[0];
  xf[b*C_+c]     = (v0-mu)*inv*bf2f(w[c]);
  xf[b*C_+c+256] = (v1-mu)*inv*bf2f(w[c+256]);
}

// ---------------- time-mix token shift: 4 outputs ----------------
__global__ __launch_bounds__(256) void tmix_mix_kernel(const float* __restrict__ xln,
    const u16* __restrict__ mk, const u16* __restrict__ mv,
    const u16* __restrict__ mr, const u16* __restrict__ mg,
    u16* __restrict__ xk, u16* __restrict__ xv, u16* __restrict__ xr, u16* __restrict__ xg){
  int row = blockIdx.x; int t = row & (T_-1);
  size_t off = (size_t)row*C_;
  const float* cur = xln + off;
  #pragma unroll
  for (int p=0;p<2;p++){
    int c = threadIdx.x + p*256;
    float xc = cur[c];
    float xp = t ? cur[c - C_] : 0.f;   // previous token (same batch), zero at t=0
    float xx = xp - xc;
    xk[off+c] = f2bf(xc + xx*bf2f(mk[c]));
    xv[off+c] = f2bf(xc + xx*bf2f(mv[c]));
    xr[off+c] = f2bf(xc + xx*bf2f(mr[c]));
    xg[off+c] = f2bf(xc + xx*bf2f(mg[c]));
  }
}

// ---------------- channel-mix token shift: 2 outputs ----------------
__global__ __launch_bounds__(256) void cmix_mix_kernel(const float* __restrict__ xln,
    const u16* __restrict__ mk, const u16* __restrict__ mr,
    u16* __restrict__ xk, u16* __restrict__ xr){
  int row = blockIdx.x; int t = row & (T_-1);
  size_t off = (size_t)row*C_;
  const float* cur = xln + off;
  #pragma unroll
  for (int p=0;p<2;p++){
    int c = threadIdx.x + p*256;
    float xc = cur[c];
    float xp = t ? cur[c - C_] : 0.f;
    float xx = xp - xc;
    xk[off+c] = f2bf(xc + xx*bf2f(mk[c]));
    xr[off+c] = f2bf(xc + xx*bf2f(mr[c]));
  }
}

// ================= MFMA GEMM: Y[M,N] = X[M,K] @ W[N,K]^T =================
// Tile 128(M)x64(N), BK=64, 24KB LDS -> 6 blocks/CU. 4 waves; wave wv computes
// rows [wv*32, wv*32+32) x all 64 cols (2x4 fragments of 16x16).
// Grid: x = M-tile (so A-strip-sharing blocks are 64 apart = same XCD), y = N-tile.
#define ACT_F32 0
#define ACT_RELU2_BF16 1
#define ACT_ADD_F32 2
#define ACT_BF16 3

template<int ACT>
__device__ __forceinline__ void gemm_mfma_body(const u16* __restrict__ X, const u16* __restrict__ W,
    float* __restrict__ Yf, u16* __restrict__ Yb, int Ndim, int Kdim, int bm, int bn){
  __shared__ __align__(16) u16 Al[128*64];   // 16 KB
  __shared__ __align__(16) u16 Bl[64*64];    // 8 KB
  const int tid = threadIdx.x;
  const int wv = tid >> 6, ln = tid & 63;
  const int m16 = ln & 15, q = ln >> 4;

  f32x4 acc[2][4];
  #pragma unroll
  for (int i=0;i<2;i++)
    #pragma unroll
    for (int j=0;j<4;j++) acc[i][j] = f32x4{0.f,0.f,0.f,0.f};

  // staging: per inst a wave writes 8 rows (64 lanes x 8 elem); 4 waves cover 32 rows/inst
  const int r0 = wv*8 + (ln >> 3);
  const int c0 = (ln & 7)*8;
  const u16* ga = X + (size_t)(bm + r0)*Kdim + c0;
  const u16* gb = W + (size_t)(bn + r0)*Kdim + c0;
  u16* la = Al + r0*64 + c0;
  u16* lb = Bl + r0*64 + c0;

  for (int k0=0; k0<Kdim; k0+=64){
    #pragma unroll
    for (int s=0;s<4;s++)
      gl_lds16(ga + (size_t)(s*32)*Kdim + k0, la + s*2048);
    #pragma unroll
    for (int s=0;s<2;s++)
      gl_lds16(gb + (size_t)(s*32)*Kdim + k0, lb + s*2048);
    __syncthreads();
    #pragma unroll
    for (int kh=0; kh<2; kh++){
      bf16x8 af[2], bfr[4];
      #pragma unroll
      for (int i=0;i<2;i++) af[i]  = *(const bf16x8*)(Al + (wv*32 + i*16 + m16)*64 + kh*32 + q*8);
      #pragma unroll
      for (int j=0;j<4;j++) bfr[j] = *(const bf16x8*)(Bl + (j*16 + m16)*64 + kh*32 + q*8);
      #pragma unroll
      for (int i=0;i<2;i++)
        #pragma unroll
        for (int j=0;j<4;j++)
          acc[i][j] = __builtin_amdgcn_mfma_f32_16x16x32_bf16(af[i], bfr[j], acc[i][j], 0, 0, 0);
    }
    __syncthreads();
  }

  // epilogue: C/D layout col=lane&15, row=quad*4+reg
  #pragma unroll
  for (int i=0;i<2;i++){
    int row = bm + wv*32 + i*16 + q*4;
    #pragma unroll
    for (int j=0;j<4;j++){
      int col = bn + j*16 + m16;
      #pragma unroll
      for (int r=0;r<4;r++){
        size_t off = (size_t)(row + r)*Ndim + col;
        float v = acc[i][j][r];
        if (ACT==ACT_F32) Yf[off] = v;
        else if (ACT==ACT_RELU2_BF16){ float rr = v>0.f ? v : 0.f; Yb[off] = f2bf(rr*rr); }
        else if (ACT==ACT_BF16) Yb[off] = f2bf(v);
        else Yf[off] += v;
      }
    }
  }
}

template<int ACT>
__global__ __launch_bounds__(256,4) void gemm_mfma(const u16* __restrict__ X, const u16* __restrict__ W,
    float* __restrict__ Yf, u16* __restrict__ Yb, int Ndim, int Kdim){
  gemm_mfma_body<ACT>(X, W, Yf, Yb, Ndim, Kdim, blockIdx.x*128, blockIdx.y*64);
}

// fused r/k/v/g projections
__global__ __launch_bounds__(256,4) void gemm4_mfma(const u16* __restrict__ Abase,
    const u16* __restrict__ W0, const u16* __restrict__ W1,
    const u16* __restrict__ W2, const u16* __restrict__ W3,
    u16* __restrict__ Obase){
  const size_t MC = (size_t)M_*C_;
  const int z = blockIdx.z;
  const u16* X; const u16* W;
  switch (z){
    case 0:  X = Abase + 2*MC; W = W0; break;   // Rb <- MR @ Wr
    case 1:  X = Abase;        W = W1; break;   // Kb <- MK @ Wk
    case 2:  X = Abase + 1*MC; W = W2; break;   // Vb <- MV @ Wv
    default: X = Abase + 3*MC; W = W3; break;   // Gb <- MG @ Wg
  }
  gemm_mfma_body<ACT_BF16>(X, W, nullptr, Obase + (size_t)z*MC, C_, C_,
                           blockIdx.x*128, blockIdx.y*64);
}

// fused cmix value+receptance GEMMs (RR must NOT alias H1)
__global__ __launch_bounds__(256,4) void gemm2_mfma(const u16* __restrict__ H1, const u16* __restrict__ Wcv,
    const u16* __restrict__ MV, const u16* __restrict__ Wcr,
    float* __restrict__ HV, float* __restrict__ RR){
  if (blockIdx.z == 0)
    gemm_mfma_body<ACT_F32>(H1, Wcv, HV, nullptr, C_, 3*C_, blockIdx.x*128, blockIdx.y*64);
  else
    gemm_mfma_body<ACT_F32>(MV, Wcr, RR, nullptr, C_, C_, blockIdx.x*128, blockIdx.y*64);
}

// ---------------- per-(b,h) transpose: Vt[(bh)*64+n][t] = Vb[(b*T+t)*C + h*64+n] ----------------
__global__ __launch_bounds__(256) void vt_transpose(const u16* __restrict__ Vb, u16* __restrict__ Vt){
  __shared__ __align__(16) u16 tile[64*64];
  const int t0 = blockIdx.x*64, bh = blockIdx.y, b = bh>>3, h = bh&7;
  const int tid = threadIdx.x;
  #pragma unroll
  for (int it=0; it<2; ++it){
    int tl = it*32 + (tid>>3);
    int n0 = (tid&7)*8;
    uint4 v = *(const uint4*)(Vb + ((size_t)(b*T_ + t0 + tl))*C_ + h*N_ + n0);
    int col = n0 ^ (((tl>>3)&7)<<3);
    *(uint4*)&tile[tl*64 + col] = v;
  }
  __syncthreads();
  #pragma unroll
  for (int it=0; it<2; ++it){
    int nl = it*32 + (tid>>3);
    int t0l = (tid&7)*8;
    int swz = (tid&7)<<3;
    union {uint4 q; u16 h2[8];} pk;
    #pragma unroll
    for (int e=0;e<8;++e)
      pk.h2[e] = tile[(t0l+e)*64 + (nl ^ swz)];
    *(uint4*)(Vt + ((size_t)(bh*N_ + nl))*T_ + t0 + t0l) = pk.q;
  }
}

// ---------------- WKV intra-chunk, MFMA: y = ((r@k^T) * Wmat) @ v ----------------
__global__ __launch_bounds__(256) void wkv_intra_mfma(const u16* __restrict__ Rb,
    const u16* __restrict__ Kb, const u16* __restrict__ Vt,
    const u16* __restrict__ td, const u16* __restrict__ tf, float* __restrict__ y){
  __shared__ float wpow[Q_];
  __shared__ __align__(16) u16 P[4][16][72];
  const int c = blockIdx.x >> 2, ip = blockIdx.x & 3;
  const int bh = blockIdx.y, b = bh >> 3, h = bh & 7;
  const int tid = threadIdx.x, wv = tid >> 6, ln = tid & 63;
  const int m16 = ln & 15, q = ln >> 4;
  const float wdec = expf(-expf(bf2f(td[h])));
  const float uu = bf2f(tf[h]);
  wpow[tid] = powf(wdec, (float)tid);
  __syncthreads();
  const size_t base = ((size_t)b*T_ + (size_t)c*Q_)*C_ + h*N_;
  const int iw0 = ip*64 + wv*16;
  const u16* rrow = Rb + base + (size_t)(iw0 + m16)*C_;
  bf16x8 af0 = *(const bf16x8*)(rrow + q*8);
  bf16x8 af1 = *(const bf16x8*)(rrow + 32 + q*8);
  f32x4 acc[4];
  #pragma unroll
  for (int nt=0;nt<4;++nt) acc[nt] = f32x4{0.f,0.f,0.f,0.f};
  const int irow = iw0 + q*4;
  const u16* vtb = Vt + (size_t)(bh*N_)*T_ + (size_t)c*Q_;
  for (int jt=0; jt<=ip; ++jt){
    f32x4 s[4];
    #pragma unroll
    for (int j2=0;j2<4;++j2) s[j2] = f32x4{0.f,0.f,0.f,0.f};
    #pragma unroll
    for (int j2=0;j2<4;++j2){
      const u16* kr = Kb + base + (size_t)(jt*64 + j2*16 + m16)*C_;
      bf16x8 b0 = *(const bf16x8*)(kr + q*8);
      bf16x8 b1 = *(const bf16x8*)(kr + 32 + q*8);
      s[j2] = __builtin_amdgcn_mfma_f32_16x16x32_bf16(af0, b0, s[j2], 0,0,0);
      s[j2] = __builtin_amdgcn_mfma_f32_16x16x32_bf16(af1, b1, s[j2], 0,0,0);
    }
    #pragma unroll
    for (int j2=0;j2<4;++j2){
      int jc = jt*64 + j2*16 + m16;
      #pragma unroll
      for (int r=0;r<4;++r){
        int ic = irow + r;
        float w = (jc < ic) ? wpow[ic-jc-1] : ((jc==ic) ? uu : 0.f);
        P[wv][q*4+r][j2*16+m16] = f2bf(s[j2][r]*w);
      }
    }
    __asm__ volatile("s_waitcnt lgkmcnt(0)" ::: "memory");
    #pragma unroll
    for (int kp=0;kp<2;++kp){
      bf16x8 ap = *(const bf16x8*)&P[wv][m16][kp*32 + q*8];
      #pragma unroll
      for (int nt=0;nt<4;++nt){
        bf16x8 bv = *(const bf16x8*)(vtb + (size_t)(nt*16 + m16)*T_ + jt*64 + kp*32 + q*8);
        acc[nt] = __builtin_amdgcn_mfma_f32_16x16x32_bf16(ap, bv, acc[nt], 0,0,0);
      }
    }
  }
  #pragma unroll
  for (int nt=0;nt<4;++nt)
    #pragma unroll
    for (int r=0;r<4;++r)
      y[base + (size_t)(irow + r)*C_ + nt*16 + m16] = acc[nt][r];
}

// ---------------- per-chunk state contribution S_c = (k*wkv)^T @ v (VALU, f32) ----------------
__global__ __launch_bounds__(256) void wkv_state(const u16* __restrict__ Kb, const u16* __restrict__ Vb,
    const u16* __restrict__ td, float* __restrict__ S){
  __shared__ float kst[64][68];
  __shared__ float vst[64][68];
  __shared__ float wpow[Q_];
  const int c = blockIdx.x, bh = blockIdx.y, b = bh>>3, h = bh&7;
  const int tid = threadIdx.x, tx = tid&15, ty = tid>>4;
  const float wdec = expf(-expf(bf2f(td[h])));
  wpow[tid] = powf(wdec, (float)tid);
  const size_t base = ((size_t)b*T_ + (size_t)c*Q_)*C_ + h*N_;
  float acc[4][4] = {};
  for (int jt=0;jt<4;++jt){
    __syncthreads();
    {
      const int rr = tid >> 6, cc2 = tid & 63;
      const int j0 = jt*64;
      for (int it=0; it<16; ++it){
        int j = it*4 + rr;
        kst[j][cc2] = bf2f(Kb[base + (size_t)(j0+j)*C_ + cc2]);
        vst[j][cc2] = bf2f(Vb[base + (size_t)(j0+j)*C_ + cc2]);
      }
    }
    __syncthreads();
    for (int jl=0;jl<64;++jl){
      float f = wpow[Q_-1-(jt*64+jl)];
      float kv[4], vv[4];
      #pragma unroll
      for (int mm=0;mm<4;mm++) kv[mm]=kst[jl][ty*4+mm]*f;
      #pragma unroll
      for (int nn=0;nn<4;nn++) vv[nn]=vst[jl][tx*4+nn];
      #pragma unroll
      for (int mm=0;mm<4;mm++)
        #pragma unroll
        for (int nn=0;nn<4;nn++) acc[mm][nn]+=kv[mm]*vv[nn];
    }
  }
  float* Sp = S + ((size_t)bh*NC_ + c)*(N_*N_);
  #pragma unroll
  for (int mm=0;mm<4;mm++)
    #pragma unroll
    for (int nn=0;nn<4;nn++)
      Sp[(ty*4+mm)*N_ + tx*4+nn] = acc[mm][nn];
}

// ---------------- sequential prefix over chunks ----------------
__global__ __launch_bounds__(256) void wkv_prefix(float* __restrict__ S, const u16* __restrict__ td){
  const int bh = blockIdx.x, h = bh&7;
  const float wdec = expf(-expf(bf2f(td[h])));
  const float wsd = powf(wdec, (float)Q_);
  float* Sp = S + (size_t)bh*NC_*N_*N_;
  for (int e=threadIdx.x; e<N_*N_; e+=256){
    float cur = 0.f;
    for (int cc=0;cc<NC_;++cc){
      float sc = Sp[(size_t)cc*N_*N_ + e];
      Sp[(size_t)cc*N_*N_ + e] = cur;
      cur = wsd*cur + sc;
    }
  }
}

// ---------------- inter-chunk: y += (r @ state_c) * wdec^i (VALU, f32) ----------------
__global__ __launch_bounds__(256) void wkv_inter(const u16* __restrict__ Rb, const float* __restrict__ S,
    const u16* __restrict__ td, float* __restrict__ y){
  __shared__ float st[64][65];
  __shared__ float rs[64][68];
  __shared__ float wpow[Q_];
  const int c = blockIdx.x>>2, ip = blockIdx.x&3;
  const int bh = blockIdx.y, b = bh>>3, h = bh&7;
  const int tid = threadIdx.x, tx = tid&15, ty = tid>>4;
  const float wdec = expf(-expf(bf2f(td[h])));
  wpow[tid] = powf(wdec, (float)tid);
  const float* Sp = S + ((size_t)bh*NC_ + c)*(N_*N_);
  for (int e=tid;e<N_*N_;e+=256) st[e>>6][e&63] = Sp[e];
  const size_t base = ((size_t)b*T_ + (size_t)c*Q_)*C_ + h*N_;
  const int i0 = ip*64;
  {
    const int rr = tid >> 6, cc2 = tid & 63;
    for (int it=0;it<16;++it){ int i=it*4+rr; rs[i][cc2]=bf2f(Rb[base+(size_t)(i0+i)*C_+cc2]); }
  }
  __syncthreads();
  float acc[4][4] = {};
  for (int kk=0;kk<N_;++kk){
    float rv[4], sv[4];
    #pragma unroll
    for (int ii=0;ii<4;ii++) rv[ii]=rs[ty*4+ii][kk];
    #pragma unroll
    for (int nn=0;nn<4;nn++) sv[nn]=st[kk][tx*4+nn];
    #pragma unroll
    for (int ii=0;ii<4;ii++)
      #pragma unroll
      for (int nn=0;nn<4;nn++) acc[ii][nn]+=rv[ii]*sv[nn];
  }
  #pragma unroll
  for (int ii=0;ii<4;ii++){
    int il = i0+ty*4+ii;
    #pragma unroll
    for (int nn=0;nn<4;nn++)
      y[base + (size_t)il*C_ + tx*4+nn] += wpow[il]*acc[ii][nn];
  }
}

// ---------------- GroupNorm over head dim + *silu(g), bf16 out ----------------
__global__ __launch_bounds__(64) void gn_kernel(const float* __restrict__ y, const u16* __restrict__ gnw,
    const u16* __restrict__ gnb, const u16* __restrict__ g, u16* __restrict__ out){
  const int id = blockIdx.x;           // (b*T_+t)*H_ + h
  const int h = id & 7;
  const size_t rowc = (size_t)(id >> 3);
  const int lane = threadIdx.x;
  const size_t off = rowc*C_ + h*N_ + lane;
  float v = y[off];
  float s = v, ss = v*v;
  #pragma unroll
  for (int o=32;o>0;o>>=1){ s+=__shfl_xor(s,o,64); ss+=__shfl_xor(ss,o,64); }
  float mu = s*(1.f/N_);
  float var = ss*(1.f/N_) - mu*mu;
  float inv = rsqrtf(fmaxf(var,0.f) + 6.4e-4f);   // GN_EPS = 1e-5*64
  int ci = h*N_+lane;
  float gg = bf2f(g[off]);
  float sil = gg/(1.f+expf(-gg));
  out[off] = f2bf(((v-mu)*inv*bf2f(gnw[ci]) + bf2f(gnb[ci]))*sil);
}

// ---------------- channel-mix tail: x += sigmoid(rr) * hv ----------------
__global__ __launch_bounds__(256) void cmix_fuse(const float* __restrict__ rr,
    const float* __restrict__ hv, float* __restrict__ x){
  size_t i = (size_t)blockIdx.x*256 + threadIdx.x;
  float r = rr[i];
  x[i] += hv[i]/(1.f+expf(-r));
}

// ---------------- logits for last position: [B,V] = xf @ wte^T ----------------
__global__ __launch_bounds__(256) void logits_kernel(const float* __restrict__ xf,
    const u16* __restrict__ wte, void* __restrict__ out, const int* __restrict__ flag){
  const int wid = threadIdx.x>>6, lane = threadIdx.x&63;
  const int gw = blockIdx.x*4 + wid;     // 0 .. B*V-1
  const int b = gw / V_, v = gw - b*V_;
  const u16* wrow = wte + (size_t)v*C_;
  const float* xr = xf + b*C_;
  union {uint4 q; u16 h[8];} uu;
  uu.q = *(const uint4*)(wrow + lane*8);
  float s = 0.f;
  #pragma unroll
  for (int j=0;j<8;j++) s += bf2f(uu.h[j])*xr[lane*8+j];
  #pragma unroll
  for (int o=32;o>0;o>>=1) s += __shfl_down(s,o,64);
  if (lane==0){
    size_t o = (size_t)b*V_ + v;
    if (*flag) ((float*)out)[o] = s;          // fp32 harness
    else       ((u16*)out)[o]   = f2bf(s);    // bf16 harness
  }
}

extern "C" void kernel_launch(void* const* d_in, const int* in_sizes, int n_in,
                              void* d_out, int out_size, void* d_ws, size_t ws_size,
                              hipStream_t stream){
  (void)out_size; (void)ws_size;
  const int* idx  = (const int*)d_in[0];

  char* ws = (char*)d_ws;
  const size_t MC  = (size_t)M_*C_;
  // ---- workspace layout (bytes) ----
  size_t o = 0;
  int* flag = (int*)(ws + o);            o += 1024;
  float* X   = (float*)(ws + o);         o += MC*4;            // fp32 residual
  float* XLN = (float*)(ws + o);         o += MC*4;            // also Y / HV
  float* Y  = XLN;  float* HV = XLN;
  u16* MK = (u16*)(ws + o);              o += MC*2;            // also YGN
  u16* MV = (u16*)(ws + o);              o += MC*2;
  u16* MR = (u16*)(ws + o);              o += MC*2;            // also S (tmix) / RR (cmix)
  u16* MG = (u16*)(ws + o);              o += MC*2;
  u16* Rb = (u16*)(ws + o);              o += MC*2;            // H1 spans Rb..Vb
  u16* Kb = (u16*)(ws + o);              o += MC*2;
  u16* Vb = (u16*)(ws + o);              o += MC*2;
  u16* Gb = (u16*)(ws + o);              o += MC*2;
  u16* Vt = (u16*)(ws + o);              o += MC*2;            // v^T per (b,h): [BH*64, T]
  float* XF = (float*)(ws + o);          o += 65536;
  u16* pool = (u16*)(ws + o);            // canonical bf16 inputs
  u16* YGN = MK;
  float* S  = (float*)MR;    // live only during tmix phase
  u16* H1 = Rb;              // [M,3C] bf16, spans Rb..Vb
  float* RR = (float*)MR;    // [M,C] f32, spans MR..MG — disjoint from H1

  // ---- dtype detect + canonicalize all non-integer inputs ----
  detect_kernel<<<1,256,0,stream>>>(d_in[12], flag);   // probe Wr
  u16* cw[24];
  {
    size_t poff = 0;
    for (int i=1;i<24;i++){ cw[i] = pool + poff; poff += (size_t)in_sizes[i]; }
  }
  for (int i=1;i<24;i++){
    int n = in_sizes[i];
    int blocks = (n + 255)/256; if (blocks > 4096) blocks = 4096;
    convert_kernel<<<blocks,256,0,stream>>>(d_in[i], cw[i], n, flag);
  }
  const u16* wte  = cw[1];  const u16* wpe  = cw[2];
  const u16* ln1w = cw[3];  const u16* ln2w = cw[4];  const u16* lnfw = cw[5];
  const u16* maak = cw[6];  const u16* maav = cw[7];
  const u16* maar = cw[8];  const u16* maag = cw[9];
  const u16* tdec = cw[10]; const u16* tfir = cw[11];
  const u16* Wr   = cw[12]; const u16* Wk   = cw[13]; const u16* Wv   = cw[14];
  const u16* Wg   = cw[15]; const u16* Wo   = cw[16];
  const u16* gnw  = cw[17]; const u16* gnb  = cw[18];
  const u16* cmk  = cw[19]; const u16* cmr  = cw[20];
  const u16* Wck  = cw[21]; const u16* Wcv  = cw[22]; const u16* Wcr  = cw[23];

  embed_kernel<<<M_,256,0,stream>>>(idx,wte,wpe,X);
  dim3 gsq(M_/128, C_/64);         // (64, 8)
  dim3 g4 (M_/128, C_/64, 4);      // fused projections
  dim3 g2 (M_/128, C_/64, 2);      // fused cmix v/r
  dim3 gck(M_/128, 3*C_/64);       // (64, 24)
  for (int l=0;l<L_;++l){
    // ---- time mix ----
    ln_kernel<<<M_,256,0,stream>>>(X, ln1w+l*C_, XLN, 1e-5f);
    tmix_mix_kernel<<<M_,256,0,stream>>>(XLN, maak+l*C_, maav+l*C_, maar+l*C_, maag+l*C_,
                                         MK,MV,MR,MG);
    gemm4_mfma<<<g4,256,0,stream>>>(MK, Wr+(size_t)l*C_*C_, Wk+(size_t)l*C_*C_,
                                    Wv+(size_t)l*C_*C_, Wg+(size_t)l*C_*C_, Rb);
    vt_transpose<<<dim3(T_/64, B_*H_),256,0,stream>>>(Vb, Vt);
    wkv_intra_mfma<<<dim3(NC_*4, B_*H_),256,0,stream>>>(Rb,Kb,Vt, tdec+l*H_, tfir+l*H_, Y);
    wkv_state<<<dim3(NC_,   B_*H_),256,0,stream>>>(Kb,Vb, tdec+l*H_, S);
    wkv_prefix<<<B_*H_,256,0,stream>>>(S, tdec+l*H_);
    wkv_inter<<<dim3(NC_*4, B_*H_),256,0,stream>>>(Rb, S, tdec+l*H_, Y);
    gn_kernel<<<M_*H_,64,0,stream>>>(Y, gnw+l*C_, gnb+l*C_, Gb, YGN);
    gemm_mfma<ACT_ADD_F32><<<gsq,256,0,stream>>>(YGN, Wo+(size_t)l*C_*C_, X, nullptr, C_, C_);
    // ---- channel mix ----
    ln_kernel<<<M_,256,0,stream>>>(X, ln2w+l*C_, XLN, 1e-5f);
    cmix_mix_kernel<<<M_,256,0,stream>>>(XLN, cmk+l*C_, cmr+l*C_, MK, MV);
    gemm_mfma<ACT_RELU2_BF16><<<gck,256,0,stream>>>(MK, Wck+(size_t)l*3*C_*C_, nullptr, H1, 3*C_, C_);
    gemm2_mfma<<<g2,256,0,stream>>>(H1, Wcv+(size_t)l*C_*3*C_, MV, Wcr+(size_t)l*C_*C_, HV, RR);
    cmix_fuse<<<(M_*C_)/256,256,0,stream>>>(RR, HV, X);
  }
  lnf_last<<<B_,256,0,stream>>>(X, lnfw, XF);
  logits_kernel<<<(B_*V_)/4,256,0,stream>>>(XF, wte, d_out, flag);
}